// Round 14
// baseline (529.828 us; speedup 1.0000x reference)
//
#include <hip/hip_runtime.h>
#include <cstdint>
#include <cstddef>

#define N_NODES 40000
#define N_EDGES 640000
#define N_GRAPH 256
#define HDIM 128
#define NLAYERS 5
#define ZDIM 257
#define SCAN_BLOCKS 157  // 157*256 = 40192 >= 40000

typedef unsigned short ushort8_t __attribute__((ext_vector_type(8)));
typedef short short8 __attribute__((ext_vector_type(8)));
typedef float float4v __attribute__((ext_vector_type(4)));

static __device__ __forceinline__ float bf2f(unsigned short h) {
    return __uint_as_float((unsigned)h << 16);
}
static __device__ __forceinline__ unsigned short f2bf(float f) {
    unsigned u = __float_as_uint(f);
    unsigned r = u + 0x7fffu + ((u >> 16) & 1u);
    return (unsigned short)(r >> 16);
}

// ---------------- embed gather: x[n,:] = embed[atoms[n],:] (f32 + bf16 shadow) ----------------
__global__ void k_embed(const int* __restrict__ atoms, const float* __restrict__ embed,
                        float* __restrict__ x, unsigned short* __restrict__ xb) {
    int i = blockIdx.x * blockDim.x + threadIdx.x;   // float4 index
    if (i >= N_NODES * 32) return;
    int n = i >> 5, c = i & 31;
    int a = atoms[n];
    float4 v = ((const float4*)embed)[(size_t)a * 32 + c];
    ((float4*)x)[(size_t)n * 32 + c] = v;
    ushort4 w;
    w.x = f2bf(v.x); w.y = f2bf(v.y); w.z = f2bf(v.z); w.w = f2bf(v.w);
    ((ushort4*)xb)[(size_t)n * 32 + c] = w;
}

// ---------------- degree histogram ----------------
__global__ void k_hist(const int* __restrict__ ei, int* __restrict__ deg) {
    int e = blockIdx.x * 256 + threadIdx.x;
    if (e >= N_EDGES) return;
    atomicAdd(&deg[ei[N_EDGES + e]], 1);
}

// ---------------- 3-phase grid-wide exclusive scan ----------------
__global__ void k_scan1(const int* __restrict__ deg, int* __restrict__ rowptr,
                        int* __restrict__ bsum) {
    __shared__ int buf[256];
    int tid = threadIdx.x;
    int i = blockIdx.x * 256 + tid;
    int v = (i < N_NODES) ? deg[i] : 0;
    buf[tid] = v;
    __syncthreads();
    for (int off = 1; off < 256; off <<= 1) {
        int t = (tid >= off) ? buf[tid - off] : 0;
        __syncthreads();
        buf[tid] += t;
        __syncthreads();
    }
    if (i < N_NODES) rowptr[i] = buf[tid] - v;   // local exclusive
    if (tid == 255) bsum[blockIdx.x] = buf[255];
}

__global__ void k_scan2(int* __restrict__ bsum, int* __restrict__ boff,
                        int* __restrict__ rowptr) {
    __shared__ int buf[256];
    int tid = threadIdx.x;
    int v = (tid < SCAN_BLOCKS) ? bsum[tid] : 0;
    buf[tid] = v;
    __syncthreads();
    for (int off = 1; off < 256; off <<= 1) {
        int t = (tid >= off) ? buf[tid - off] : 0;
        __syncthreads();
        buf[tid] += t;
        __syncthreads();
    }
    if (tid < SCAN_BLOCKS) boff[tid] = buf[tid] - v;  // exclusive block offset
    if (tid == 255) rowptr[N_NODES] = buf[255];
}

__global__ void k_scan3(const int* __restrict__ boff, int* __restrict__ rowptr,
                        int* __restrict__ cursor) {
    int i = blockIdx.x * 256 + threadIdx.x;
    if (i >= N_NODES) return;
    int e = rowptr[i] + boff[blockIdx.x];
    rowptr[i] = e;
    cursor[i] = e;
}

// ---------------- scatter edges into CSR (by dst), computing ea inline ----------------
__global__ void k_scatter(const int* __restrict__ ei, const float* __restrict__ pos,
                          int* __restrict__ cursor, int2* __restrict__ csr) {
    int e = blockIdx.x * 256 + threadIdx.x;
    if (e >= N_EDGES) return;
    int s = ei[e], d = ei[N_EDGES + e];
    float dx = pos[3 * s] - pos[3 * d];
    float dy = pos[3 * s + 1] - pos[3 * d + 1];
    float dz = pos[3 * s + 2] - pos[3 * d + 2];
    float ea = sqrtf(dx * dx + dy * dy + dz * dz);
    int p = atomicAdd(&cursor[d], 1);
    csr[p] = make_int2(s, __float_as_int(ea));
}

// ---------------- graph boundaries from sorted batch ----------------
__global__ void k_gbound(const int* __restrict__ batch, int* __restrict__ gstart) {
    int g = blockIdx.x * 256 + threadIdx.x;
    if (g > N_GRAPH) return;
    if (g == N_GRAPH) { gstart[g] = N_NODES; return; }
    int lo = 0, hi = N_NODES;
    while (lo < hi) {
        int mid = (lo + hi) >> 1;
        if (batch[mid] < g) lo = mid + 1; else hi = mid;
    }
    gstart[g] = lo;
}

// ---------------- pack ALL 5 layers' weights -> Wp bf16 [l][n=512][k=128] ----------------
__global__ void k_pack(const float* __restrict__ lin_f_w, const float* __restrict__ lin_s_w,
                       unsigned short* __restrict__ Wp, float* __restrict__ wfe,
                       float* __restrict__ wse) {
    int l = blockIdx.y;
    const float* wf = lin_f_w + (size_t)l * HDIM * ZDIM;
    const float* ws = lin_s_w + (size_t)l * HDIM * ZDIM;
    unsigned short* Wpl = Wp + (size_t)l * 512 * 128;
    int i = blockIdx.x * 256 + threadIdx.x;
    if (i < 512 * 128) {
        int n = i >> 7, k = i & 127;
        int blk = n >> 8;        // 0 = src block, 1 = dst block
        int cc = n & 255;
        int t = cc & 3;
        int ch = 2 * (cc >> 2) + (t & 1);
        const float* W = (t < 2) ? wf : ws;
        int col = blk ? k : (128 + k);
        Wpl[i] = f2bf(W[ch * ZDIM + col]);
    } else if (i < 512 * 128 + 256) {
        int j = i - 512 * 128;
        if (j < 128) wfe[l * 128 + j] = wf[j * ZDIM + 256];
        else wse[l * 128 + (j - 128)] = ws[(j - 128) * ZDIM + 256];
    }
}

// ---------------- MFMA node GEMM (merged cols): P[n,512] = xb[n,128] @ Wp[128,512] (+bias) ----------------
// grid 625: 64-row tiles, 512 cols per block. 8 waves, wave w = cols [w*64,+64) x 64 rows.
// UNCHANGED from R13 — this round is about getting its counters into the top-5.
__launch_bounds__(512, 4)
__global__ void k_gemm(const unsigned short* __restrict__ xb,
                       const unsigned short* __restrict__ Wp,
                       const float* __restrict__ bf, const float* __restrict__ bs,
                       unsigned short* __restrict__ P) {
    __shared__ unsigned short smem[32 * 512];    // 32 KB
    unsigned short* A = smem;                    // A tile: 64 rows x 128 k (16 KB)
    const int row0 = blockIdx.x * 64;
    const int tid = threadIdx.x;

    {
        int r = tid >> 3, sub = tid & 7;
        const ushort8_t* src = (const ushort8_t*)(xb + (size_t)(row0 + r) * 128 + sub * 16);
        ushort8_t v0 = src[0], v1 = src[1];
        int h = r & 7;
        *(ushort8_t*)(A + r * 128 + (((sub * 2) ^ h) * 8)) = v0;
        *(ushort8_t*)(A + r * 128 + (((sub * 2 + 1) ^ h) * 8)) = v1;
    }
    __syncthreads();

    const int wid = tid >> 6, lane = tid & 63;
    const int l16 = lane & 15, lg = lane >> 4;

    float4v acc[4][4];
#pragma unroll
    for (int i = 0; i < 4; ++i)
#pragma unroll
        for (int j = 0; j < 4; ++j) acc[i][j] = (float4v){0.f, 0.f, 0.f, 0.f};

#pragma unroll
    for (int ks = 0; ks < 4; ++ks) {             // K = 128 in steps of 32
        short8 bfr[4];
#pragma unroll
        for (int cf = 0; cf < 4; ++cf) {
            int n = wid * 64 + cf * 16 + l16;
            bfr[cf] = *(const short8*)(Wp + (size_t)n * 128 + ks * 32 + lg * 8);
        }
#pragma unroll
        for (int rf = 0; rf < 4; ++rf) {
            int row = rf * 16 + l16;
            int kg = ks * 4 + lg;
            short8 af = *(const short8*)(A + row * 128 + ((kg ^ (row & 7)) * 8));
#pragma unroll
            for (int cf = 0; cf < 4; ++cf)
                acc[rf][cf] = __builtin_amdgcn_mfma_f32_16x16x32_bf16(
                    af, bfr[cf], acc[rf][cf], 0, 0, 0);
        }
    }

    float bias[4];
#pragma unroll
    for (int cf = 0; cf < 4; ++cf) {
        int n = wid * 64 + cf * 16 + l16;
        if (n < 256) bias[cf] = 0.f;
        else {
            int cc = n - 256;
            int t = cc & 3;
            int ch = 2 * (cc >> 2) + (t & 1);
            bias[cf] = (t < 2) ? bf[ch] : bs[ch];
        }
    }

#pragma unroll
    for (int p = 0; p < 2; ++p) {
        __syncthreads();
#pragma unroll
        for (int rfl = 0; rfl < 2; ++rfl) {
            int rf = 2 * p + rfl;
#pragma unroll
            for (int cf = 0; cf < 4; ++cf) {
                int col = wid * 64 + cf * 16 + l16;
#pragma unroll
                for (int r = 0; r < 4; ++r) {
                    int rowl = rfl * 16 + lg * 4 + r;     // 0..31
                    smem[rowl * 512 + col] = f2bf(acc[rf][cf][r] + bias[cf]);
                }
            }
        }
        __syncthreads();
#pragma unroll
        for (int i = 0; i < 4; ++i) {
            int u = i * 512 + tid;
            int rw = u >> 6, ch = u & 63;
            *(ushort8_t*)(P + (size_t)(row0 + p * 32 + rw) * 512 + ch * 8) =
                *(const ushort8_t*)(smem + rw * 512 + ch * 8);
        }
    }
}

// ---------------- CSR edge kernel: one wave per dst node; HALF-RANGE dispatches ----------------
__launch_bounds__(64)
__global__ void k_edge_csr(const unsigned short* __restrict__ P,
                           const float* __restrict__ wfe, const float* __restrict__ wse,
                           const int* __restrict__ rowptr, const int2* __restrict__ csr,
                           float* __restrict__ x, unsigned short* __restrict__ xb,
                           int node_base) {
    int node = node_base + blockIdx.x;
    int lane = threadIdx.x;
    int beg = rowptr[node], end = rowptr[node + 1];
    ushort4 dv = *(const ushort4*)(P + (size_t)node * 512 + 256 + 4 * lane);
    float fi0 = bf2f(dv.x), fi1 = bf2f(dv.y);
    float si0 = bf2f(dv.z), si1 = bf2f(dv.w);
    float2 wf = ((const float2*)wfe)[lane];
    float2 wsv = ((const float2*)wse)[lane];
    float acc0 = 0.f, acc1 = 0.f;
    const float LOG2E = 1.44269504f, LN2 = 0.69314718f;

    auto edge_math = [&](ushort4 sv, float eav) {
        float g0 = fi0 + bf2f(sv.x) + eav * wf.x;
        float g1 = fi1 + bf2f(sv.y) + eav * wf.y;
        float c0 = si0 + bf2f(sv.z) + eav * wsv.x;
        float c1 = si1 + bf2f(sv.w) + eav * wsv.y;
        float sg0 = __builtin_amdgcn_rcpf(1.f + __builtin_amdgcn_exp2f(-g0 * LOG2E));
        float sg1 = __builtin_amdgcn_rcpf(1.f + __builtin_amdgcn_exp2f(-g1 * LOG2E));
        float a0 = fabsf(c0), a1 = fabsf(c1);
        float l0 = __builtin_amdgcn_logf(1.f + __builtin_amdgcn_exp2f(-a0 * LOG2E)) * LN2;
        float l1 = __builtin_amdgcn_logf(1.f + __builtin_amdgcn_exp2f(-a1 * LOG2E)) * LN2;
        float sp0 = fmaxf(c0, 0.f) + l0;
        float sp1 = fmaxf(c1, 0.f) + l1;
        acc0 += sg0 * sp0;
        acc1 += sg1 * sp1;
    };

    int e = beg;
    for (; e + 4 <= end; e += 4) {
        int2 c0 = csr[e];
        int2 c1 = csr[e + 1];
        int2 c2 = csr[e + 2];
        int2 c3 = csr[e + 3];
        int s0 = __builtin_amdgcn_readfirstlane(c0.x);
        float ea0 = __uint_as_float(__builtin_amdgcn_readfirstlane((unsigned)c0.y));
        int s1 = __builtin_amdgcn_readfirstlane(c1.x);
        float ea1 = __uint_as_float(__builtin_amdgcn_readfirstlane((unsigned)c1.y));
        int s2 = __builtin_amdgcn_readfirstlane(c2.x);
        float ea2 = __uint_as_float(__builtin_amdgcn_readfirstlane((unsigned)c2.y));
        int s3 = __builtin_amdgcn_readfirstlane(c3.x);
        float ea3 = __uint_as_float(__builtin_amdgcn_readfirstlane((unsigned)c3.y));
        ushort4 sv0 = *(const ushort4*)(P + (size_t)s0 * 512 + 4 * lane);
        ushort4 sv1 = *(const ushort4*)(P + (size_t)s1 * 512 + 4 * lane);
        ushort4 sv2 = *(const ushort4*)(P + (size_t)s2 * 512 + 4 * lane);
        ushort4 sv3 = *(const ushort4*)(P + (size_t)s3 * 512 + 4 * lane);
        edge_math(sv0, ea0);
        edge_math(sv1, ea1);
        edge_math(sv2, ea2);
        edge_math(sv3, ea3);
    }
    for (; e < end; ++e) {
        int2 c0 = csr[e];
        int s0 = __builtin_amdgcn_readfirstlane(c0.x);
        float ea0 = __uint_as_float(__builtin_amdgcn_readfirstlane((unsigned)c0.y));
        ushort4 sv0 = *(const ushort4*)(P + (size_t)s0 * 512 + 4 * lane);
        edge_math(sv0, ea0);
    }

    float2* xd = (float2*)(x + (size_t)node * 128) + lane;
    float2 xv = *xd;
    xv.x += acc0;
    xv.y += acc1;
    *xd = xv;
    ushort2 xbv;
    xbv.x = f2bf(xv.x);
    xbv.y = f2bf(xv.y);
    ((ushort2*)(xb + (size_t)node * 128))[lane] = xbv;
}

// ---------------- fused mean-pool (2-way node-parallel) + FC head ----------------
__launch_bounds__(256)
__global__ void k_poolfc(const float* __restrict__ x, const int* __restrict__ gstart,
                         const float* __restrict__ fc_w, const float* __restrict__ fc_b,
                         const float* __restrict__ out_w, const float* __restrict__ out_b,
                         float* __restrict__ out) {
    int g = blockIdx.x;
    int tid = threadIdx.x;
    int h = tid & 127;
    int half = tid >> 7;                 // 0: even nodes, 1: odd nodes
    int s = gstart[g], e = gstart[g + 1];
    float sum = 0.f;
    for (int n = s + half; n < e; n += 2) sum += x[(size_t)n * HDIM + h];
    __shared__ float part[256];
    __shared__ float gin[128];
    __shared__ float gout[128];
    part[tid] = sum;
    __syncthreads();
    float cnt = fmaxf((float)(e - s), 1.0f);
    if (tid < 128) gin[h] = (part[h] + part[h + 128]) / cnt;
    __syncthreads();
    for (int l = 0; l < 3; ++l) {
        float acc = 0.f;
        if (tid < 128) {
            const float* W = fc_w + (size_t)l * HDIM * HDIM + (size_t)h * HDIM;
            acc = fc_b[l * HDIM + h];
#pragma unroll 4
            for (int k = 0; k < HDIM; k += 4) {
                float4 w4 = *(const float4*)(W + k);
                acc += gin[k] * w4.x + gin[k + 1] * w4.y + gin[k + 2] * w4.z + gin[k + 3] * w4.w;
            }
        }
        __syncthreads();
        if (tid < 128) gout[h] = acc;
        __syncthreads();
        if (tid < 128) gin[h] = gout[h];
        __syncthreads();
    }
    if (tid < 128) gout[h] = gin[h] * out_w[h];
    __syncthreads();
    if (tid < 64) gout[tid] += gout[tid + 64];
    __syncthreads();
    if (tid == 0) {
        float acc = 0.f;
        for (int i = 0; i < 64; ++i) acc += gout[i];
        out[g] = acc + out_b[0];
    }
}

extern "C" void kernel_launch(void* const* d_in, const int* in_sizes, int n_in,
                              void* d_out, int out_size, void* d_ws, size_t ws_size,
                              hipStream_t stream) {
    const int* atoms = (const int*)d_in[0];
    const float* pos = (const float*)d_in[1];
    const int* ei = (const int*)d_in[2];
    const int* batch = (const int*)d_in[3];
    const float* embed = (const float*)d_in[4];
    const float* lin_f_w = (const float*)d_in[5];
    const float* lin_f_b = (const float*)d_in[6];
    const float* lin_s_w = (const float*)d_in[7];
    const float* lin_s_b = (const float*)d_in[8];
    const float* fc_w = (const float*)d_in[9];
    const float* fc_b = (const float*)d_in[10];
    const float* out_w = (const float*)d_in[11];
    const float* out_b = (const float*)d_in[12];
    float* out = (float*)d_out;

    char* ws = (char*)d_ws;
    size_t off = 0;
    auto alloc = [&](size_t bytes) -> void* {
        void* p = ws + off;
        off += (bytes + 255) & ~(size_t)255;
        return p;
    };
    float* x            = (float*)alloc((size_t)N_NODES * HDIM * 4);
    unsigned short* xb  = (unsigned short*)alloc((size_t)N_NODES * HDIM * 2);
    unsigned short* P   = (unsigned short*)alloc((size_t)N_NODES * 512 * 2);
    unsigned short* Wp  = (unsigned short*)alloc((size_t)NLAYERS * 512 * 128 * 2);
    float* wfe          = (float*)alloc((size_t)NLAYERS * 128 * 4);
    float* wse          = (float*)alloc((size_t)NLAYERS * 128 * 4);
    int* deg            = (int*)alloc((size_t)N_NODES * 4);
    int* rowptr         = (int*)alloc((size_t)(N_NODES + 1) * 4);
    int* cursor         = (int*)alloc((size_t)N_NODES * 4);
    int* gstart         = (int*)alloc((size_t)(N_GRAPH + 1) * 4);
    int* bsum           = (int*)alloc((size_t)SCAN_BLOCKS * 4);
    int* boff           = (int*)alloc((size_t)SCAN_BLOCKS * 4);
    int2* csr           = (int2*)alloc((size_t)N_EDGES * 8);

    hipMemsetAsync(deg, 0, (size_t)N_NODES * 4, stream);

    k_embed<<<(N_NODES * 32 + 255) / 256, 256, 0, stream>>>(atoms, embed, x, xb);
    k_hist<<<(N_EDGES + 255) / 256, 256, 0, stream>>>(ei, deg);
    k_scan1<<<SCAN_BLOCKS, 256, 0, stream>>>(deg, rowptr, bsum);
    k_scan2<<<1, 256, 0, stream>>>(bsum, boff, rowptr);
    k_scan3<<<SCAN_BLOCKS, 256, 0, stream>>>(boff, rowptr, cursor);
    k_scatter<<<(N_EDGES + 255) / 256, 256, 0, stream>>>(ei, pos, cursor, csr);
    k_gbound<<<2, 256, 0, stream>>>(batch, gstart);
    k_pack<<<dim3(257, NLAYERS), 256, 0, stream>>>(lin_f_w, lin_s_w, Wp, wfe, wse);

    for (int l = 0; l < NLAYERS; ++l) {
        k_gemm<<<625, 512, 0, stream>>>(xb, Wp + (size_t)l * 512 * 128,
                                        lin_f_b + (size_t)l * HDIM,
                                        lin_s_b + (size_t)l * HDIM, P);
        k_edge_csr<<<N_NODES / 2, 64, 0, stream>>>(P, wfe + (size_t)l * 128,
                                                   wse + (size_t)l * 128, rowptr, csr,
                                                   x, xb, 0);
        k_edge_csr<<<N_NODES / 2, 64, 0, stream>>>(P, wfe + (size_t)l * 128,
                                                   wse + (size_t)l * 128, rowptr, csr,
                                                   x, xb, N_NODES / 2);
    }

    k_poolfc<<<N_GRAPH, 256, 0, stream>>>(x, gstart, fc_w, fc_b, out_w, out_b, out);
}

// Round 15
// 486.969 us; speedup vs baseline: 1.0880x; 1.0880x over previous
//
#include <hip/hip_runtime.h>
#include <cstdint>
#include <cstddef>

#define N_NODES 40000
#define N_EDGES 640000
#define N_GRAPH 256
#define HDIM 128
#define NLAYERS 5
#define ZDIM 257
#define SCAN_BLOCKS 157  // 157*256 = 40192 >= 40000
#define EP_STRIDE 520    // epilogue LDS row stride (ushorts): 1040 B = 16 mod 128 -> no 4-way conflict

typedef unsigned short ushort8_t __attribute__((ext_vector_type(8)));
typedef short short8 __attribute__((ext_vector_type(8)));
typedef float float4v __attribute__((ext_vector_type(4)));

static __device__ __forceinline__ float bf2f(unsigned short h) {
    return __uint_as_float((unsigned)h << 16);
}
static __device__ __forceinline__ unsigned short f2bf(float f) {
    unsigned u = __float_as_uint(f);
    unsigned r = u + 0x7fffu + ((u >> 16) & 1u);
    return (unsigned short)(r >> 16);
}

// ---------------- fused: embed gather + degree histogram ----------------
__global__ void k_embed_hist(const int* __restrict__ atoms, const float* __restrict__ embed,
                             const int* __restrict__ ei, float* __restrict__ x,
                             unsigned short* __restrict__ xb, int* __restrict__ deg) {
    int i = blockIdx.x * blockDim.x + threadIdx.x;
    if (i < N_NODES * 32) {
        int n = i >> 5, c = i & 31;
        int a = atoms[n];
        float4 v = ((const float4*)embed)[(size_t)a * 32 + c];
        ((float4*)x)[(size_t)n * 32 + c] = v;
        ushort4 w;
        w.x = f2bf(v.x); w.y = f2bf(v.y); w.z = f2bf(v.z); w.w = f2bf(v.w);
        ((ushort4*)xb)[(size_t)n * 32 + c] = w;
    }
    if (i < N_EDGES) {
        atomicAdd(&deg[ei[N_EDGES + i]], 1);
    }
}

// ---------------- 3-phase grid-wide exclusive scan ----------------
__global__ void k_scan1(const int* __restrict__ deg, int* __restrict__ rowptr,
                        int* __restrict__ bsum) {
    __shared__ int buf[256];
    int tid = threadIdx.x;
    int i = blockIdx.x * 256 + tid;
    int v = (i < N_NODES) ? deg[i] : 0;
    buf[tid] = v;
    __syncthreads();
    for (int off = 1; off < 256; off <<= 1) {
        int t = (tid >= off) ? buf[tid - off] : 0;
        __syncthreads();
        buf[tid] += t;
        __syncthreads();
    }
    if (i < N_NODES) rowptr[i] = buf[tid] - v;   // local exclusive
    if (tid == 255) bsum[blockIdx.x] = buf[255];
}

// phase 2 + graph boundaries (fused): one block does both
__global__ void k_scan2g(int* __restrict__ bsum, int* __restrict__ boff,
                         int* __restrict__ rowptr, const int* __restrict__ batch,
                         int* __restrict__ gstart) {
    __shared__ int buf[256];
    int tid = threadIdx.x;
    int v = (tid < SCAN_BLOCKS) ? bsum[tid] : 0;
    buf[tid] = v;
    __syncthreads();
    for (int off = 1; off < 256; off <<= 1) {
        int t = (tid >= off) ? buf[tid - off] : 0;
        __syncthreads();
        buf[tid] += t;
        __syncthreads();
    }
    if (tid < SCAN_BLOCKS) boff[tid] = buf[tid] - v;  // exclusive block offset
    if (tid == 255) rowptr[N_NODES] = buf[255];
    // gbound: g = tid (binary search sorted batch)
    {
        int g = tid;
        int lo = 0, hi = N_NODES;
        while (lo < hi) {
            int mid = (lo + hi) >> 1;
            if (batch[mid] < g) lo = mid + 1; else hi = mid;
        }
        gstart[g] = lo;
        if (tid == 0) gstart[N_GRAPH] = N_NODES;
    }
}

__global__ void k_scan3(const int* __restrict__ boff, int* __restrict__ rowptr,
                        int* __restrict__ cursor) {
    int i = blockIdx.x * 256 + threadIdx.x;
    if (i >= N_NODES) return;
    int e = rowptr[i] + boff[blockIdx.x];
    rowptr[i] = e;
    cursor[i] = e;
}

// ---------------- scatter edges into CSR (by dst), computing ea inline ----------------
__global__ void k_scatter(const int* __restrict__ ei, const float* __restrict__ pos,
                          int* __restrict__ cursor, int2* __restrict__ csr) {
    int e = blockIdx.x * 256 + threadIdx.x;
    if (e >= N_EDGES) return;
    int s = ei[e], d = ei[N_EDGES + e];
    float dx = pos[3 * s] - pos[3 * d];
    float dy = pos[3 * s + 1] - pos[3 * d + 1];
    float dz = pos[3 * s + 2] - pos[3 * d + 2];
    float ea = sqrtf(dx * dx + dy * dy + dz * dz);
    int p = atomicAdd(&cursor[d], 1);
    csr[p] = make_int2(s, __float_as_int(ea));
}

// ---------------- pack ALL 5 layers' weights -> Wp bf16 [l][n=512][k=128] ----------------
__global__ void k_pack(const float* __restrict__ lin_f_w, const float* __restrict__ lin_s_w,
                       unsigned short* __restrict__ Wp, float* __restrict__ wfe,
                       float* __restrict__ wse) {
    int l = blockIdx.y;
    const float* wf = lin_f_w + (size_t)l * HDIM * ZDIM;
    const float* ws = lin_s_w + (size_t)l * HDIM * ZDIM;
    unsigned short* Wpl = Wp + (size_t)l * 512 * 128;
    int i = blockIdx.x * 256 + threadIdx.x;
    if (i < 512 * 128) {
        int n = i >> 7, k = i & 127;
        int blk = n >> 8;        // 0 = src block, 1 = dst block
        int cc = n & 255;
        int t = cc & 3;
        int ch = 2 * (cc >> 2) + (t & 1);
        const float* W = (t < 2) ? wf : ws;
        int col = blk ? k : (128 + k);
        Wpl[i] = f2bf(W[ch * ZDIM + col]);
    } else if (i < 512 * 128 + 256) {
        int j = i - 512 * 128;
        if (j < 128) wfe[l * 128 + j] = wf[j * ZDIM + 256];
        else wse[l * 128 + (j - 128)] = ws[(j - 128) * ZDIM + 256];
    }
}

// ---------------- MFMA node GEMM (merged cols): P[n,512] = xb[n,128] @ Wp[128,512] (+bias) ----------------
// grid 625: 64-row tiles, 512 cols per block. 8 waves, wave w = cols [w*64,+64) x 64 rows.
// Epilogue LDS padded to EP_STRIDE=520 ushorts/row: kills the 4-way bank conflict of the
// unpadded 512-stride (1024 B row stride == 0 mod 128 put all 4 lg-groups on the same 8 banks).
__launch_bounds__(512, 4)
__global__ void k_gemm(const unsigned short* __restrict__ xb,
                       const unsigned short* __restrict__ Wp,
                       const float* __restrict__ bf, const float* __restrict__ bs,
                       unsigned short* __restrict__ P) {
    __shared__ unsigned short smem[32 * EP_STRIDE];  // 32.5 KB; A tile uses first 16 KB
    unsigned short* A = smem;                        // A tile: 64 rows x 128 k
    const int row0 = blockIdx.x * 64;
    const int tid = threadIdx.x;

    {
        int r = tid >> 3, sub = tid & 7;
        const ushort8_t* src = (const ushort8_t*)(xb + (size_t)(row0 + r) * 128 + sub * 16);
        ushort8_t v0 = src[0], v1 = src[1];
        int h = r & 7;
        *(ushort8_t*)(A + r * 128 + (((sub * 2) ^ h) * 8)) = v0;
        *(ushort8_t*)(A + r * 128 + (((sub * 2 + 1) ^ h) * 8)) = v1;
    }
    __syncthreads();

    const int wid = tid >> 6, lane = tid & 63;
    const int l16 = lane & 15, lg = lane >> 4;

    float4v acc[4][4];
#pragma unroll
    for (int i = 0; i < 4; ++i)
#pragma unroll
        for (int j = 0; j < 4; ++j) acc[i][j] = (float4v){0.f, 0.f, 0.f, 0.f};

#pragma unroll
    for (int ks = 0; ks < 4; ++ks) {             // K = 128 in steps of 32
        short8 bfr[4];
#pragma unroll
        for (int cf = 0; cf < 4; ++cf) {
            int n = wid * 64 + cf * 16 + l16;
            bfr[cf] = *(const short8*)(Wp + (size_t)n * 128 + ks * 32 + lg * 8);
        }
#pragma unroll
        for (int rf = 0; rf < 4; ++rf) {
            int row = rf * 16 + l16;
            int kg = ks * 4 + lg;
            short8 af = *(const short8*)(A + row * 128 + ((kg ^ (row & 7)) * 8));
#pragma unroll
            for (int cf = 0; cf < 4; ++cf)
                acc[rf][cf] = __builtin_amdgcn_mfma_f32_16x16x32_bf16(
                    af, bfr[cf], acc[rf][cf], 0, 0, 0);
        }
    }

    float bias[4];
#pragma unroll
    for (int cf = 0; cf < 4; ++cf) {
        int n = wid * 64 + cf * 16 + l16;
        if (n < 256) bias[cf] = 0.f;
        else {
            int cc = n - 256;
            int t = cc & 3;
            int ch = 2 * (cc >> 2) + (t & 1);
            bias[cf] = (t < 2) ? bf[ch] : bs[ch];
        }
    }

#pragma unroll
    for (int p = 0; p < 2; ++p) {
        __syncthreads();
#pragma unroll
        for (int rfl = 0; rfl < 2; ++rfl) {
            int rf = 2 * p + rfl;
#pragma unroll
            for (int cf = 0; cf < 4; ++cf) {
                int col = wid * 64 + cf * 16 + l16;
#pragma unroll
                for (int r = 0; r < 4; ++r) {
                    int rowl = rfl * 16 + lg * 4 + r;     // 0..31
                    smem[rowl * EP_STRIDE + col] = f2bf(acc[rf][cf][r] + bias[cf]);
                }
            }
        }
        __syncthreads();
#pragma unroll
        for (int i = 0; i < 4; ++i) {
            int u = i * 512 + tid;
            int rw = u >> 6, ch = u & 63;
            *(ushort8_t*)(P + (size_t)(row0 + p * 32 + rw) * 512 + ch * 8) =
                *(const ushort8_t*)(smem + rw * EP_STRIDE + ch * 8);
        }
    }
}

// ---------------- CSR edge kernel: one wave per dst node, 4 edges in flight ----------------
__launch_bounds__(64)
__global__ void k_edge_csr(const unsigned short* __restrict__ P,
                           const float* __restrict__ wfe, const float* __restrict__ wse,
                           const int* __restrict__ rowptr, const int2* __restrict__ csr,
                           float* __restrict__ x, unsigned short* __restrict__ xb) {
    int node = blockIdx.x;
    int lane = threadIdx.x;
    int beg = rowptr[node], end = rowptr[node + 1];
    ushort4 dv = *(const ushort4*)(P + (size_t)node * 512 + 256 + 4 * lane);
    float fi0 = bf2f(dv.x), fi1 = bf2f(dv.y);
    float si0 = bf2f(dv.z), si1 = bf2f(dv.w);
    float2 wf = ((const float2*)wfe)[lane];
    float2 wsv = ((const float2*)wse)[lane];
    float acc0 = 0.f, acc1 = 0.f;
    const float LOG2E = 1.44269504f, LN2 = 0.69314718f;

    auto edge_math = [&](ushort4 sv, float eav) {
        float g0 = fi0 + bf2f(sv.x) + eav * wf.x;
        float g1 = fi1 + bf2f(sv.y) + eav * wf.y;
        float c0 = si0 + bf2f(sv.z) + eav * wsv.x;
        float c1 = si1 + bf2f(sv.w) + eav * wsv.y;
        float sg0 = __builtin_amdgcn_rcpf(1.f + __builtin_amdgcn_exp2f(-g0 * LOG2E));
        float sg1 = __builtin_amdgcn_rcpf(1.f + __builtin_amdgcn_exp2f(-g1 * LOG2E));
        float a0 = fabsf(c0), a1 = fabsf(c1);
        float l0 = __builtin_amdgcn_logf(1.f + __builtin_amdgcn_exp2f(-a0 * LOG2E)) * LN2;
        float l1 = __builtin_amdgcn_logf(1.f + __builtin_amdgcn_exp2f(-a1 * LOG2E)) * LN2;
        float sp0 = fmaxf(c0, 0.f) + l0;
        float sp1 = fmaxf(c1, 0.f) + l1;
        acc0 += sg0 * sp0;
        acc1 += sg1 * sp1;
    };

    int e = beg;
    for (; e + 4 <= end; e += 4) {
        int2 c0 = csr[e];
        int2 c1 = csr[e + 1];
        int2 c2 = csr[e + 2];
        int2 c3 = csr[e + 3];
        int s0 = __builtin_amdgcn_readfirstlane(c0.x);
        float ea0 = __uint_as_float(__builtin_amdgcn_readfirstlane((unsigned)c0.y));
        int s1 = __builtin_amdgcn_readfirstlane(c1.x);
        float ea1 = __uint_as_float(__builtin_amdgcn_readfirstlane((unsigned)c1.y));
        int s2 = __builtin_amdgcn_readfirstlane(c2.x);
        float ea2 = __uint_as_float(__builtin_amdgcn_readfirstlane((unsigned)c2.y));
        int s3 = __builtin_amdgcn_readfirstlane(c3.x);
        float ea3 = __uint_as_float(__builtin_amdgcn_readfirstlane((unsigned)c3.y));
        ushort4 sv0 = *(const ushort4*)(P + (size_t)s0 * 512 + 4 * lane);
        ushort4 sv1 = *(const ushort4*)(P + (size_t)s1 * 512 + 4 * lane);
        ushort4 sv2 = *(const ushort4*)(P + (size_t)s2 * 512 + 4 * lane);
        ushort4 sv3 = *(const ushort4*)(P + (size_t)s3 * 512 + 4 * lane);
        edge_math(sv0, ea0);
        edge_math(sv1, ea1);
        edge_math(sv2, ea2);
        edge_math(sv3, ea3);
    }
    for (; e < end; ++e) {
        int2 c0 = csr[e];
        int s0 = __builtin_amdgcn_readfirstlane(c0.x);
        float ea0 = __uint_as_float(__builtin_amdgcn_readfirstlane((unsigned)c0.y));
        ushort4 sv0 = *(const ushort4*)(P + (size_t)s0 * 512 + 4 * lane);
        edge_math(sv0, ea0);
    }

    float2* xd = (float2*)(x + (size_t)node * 128) + lane;
    float2 xv = *xd;
    xv.x += acc0;
    xv.y += acc1;
    *xd = xv;
    ushort2 xbv;
    xbv.x = f2bf(xv.x);
    xbv.y = f2bf(xv.y);
    ((ushort2*)(xb + (size_t)node * 128))[lane] = xbv;
}

// ---------------- fused mean-pool (2-way node-parallel) + FC head ----------------
__launch_bounds__(256)
__global__ void k_poolfc(const float* __restrict__ x, const int* __restrict__ gstart,
                         const float* __restrict__ fc_w, const float* __restrict__ fc_b,
                         const float* __restrict__ out_w, const float* __restrict__ out_b,
                         float* __restrict__ out) {
    int g = blockIdx.x;
    int tid = threadIdx.x;
    int h = tid & 127;
    int half = tid >> 7;                 // 0: even nodes, 1: odd nodes
    int s = gstart[g], e = gstart[g + 1];
    float sum = 0.f;
    for (int n = s + half; n < e; n += 2) sum += x[(size_t)n * HDIM + h];
    __shared__ float part[256];
    __shared__ float gin[128];
    __shared__ float gout[128];
    part[tid] = sum;
    __syncthreads();
    float cnt = fmaxf((float)(e - s), 1.0f);
    if (tid < 128) gin[h] = (part[h] + part[h + 128]) / cnt;
    __syncthreads();
    for (int l = 0; l < 3; ++l) {
        float acc = 0.f;
        if (tid < 128) {
            const float* W = fc_w + (size_t)l * HDIM * HDIM + (size_t)h * HDIM;
            acc = fc_b[l * HDIM + h];
#pragma unroll 4
            for (int k = 0; k < HDIM; k += 4) {
                float4 w4 = *(const float4*)(W + k);
                acc += gin[k] * w4.x + gin[k + 1] * w4.y + gin[k + 2] * w4.z + gin[k + 3] * w4.w;
            }
        }
        __syncthreads();
        if (tid < 128) gout[h] = acc;
        __syncthreads();
        if (tid < 128) gin[h] = gout[h];
        __syncthreads();
    }
    if (tid < 128) gout[h] = gin[h] * out_w[h];
    __syncthreads();
    if (tid < 64) gout[tid] += gout[tid + 64];
    __syncthreads();
    if (tid == 0) {
        float acc = 0.f;
        for (int i = 0; i < 64; ++i) acc += gout[i];
        out[g] = acc + out_b[0];
    }
}

extern "C" void kernel_launch(void* const* d_in, const int* in_sizes, int n_in,
                              void* d_out, int out_size, void* d_ws, size_t ws_size,
                              hipStream_t stream) {
    const int* atoms = (const int*)d_in[0];
    const float* pos = (const float*)d_in[1];
    const int* ei = (const int*)d_in[2];
    const int* batch = (const int*)d_in[3];
    const float* embed = (const float*)d_in[4];
    const float* lin_f_w = (const float*)d_in[5];
    const float* lin_f_b = (const float*)d_in[6];
    const float* lin_s_w = (const float*)d_in[7];
    const float* lin_s_b = (const float*)d_in[8];
    const float* fc_w = (const float*)d_in[9];
    const float* fc_b = (const float*)d_in[10];
    const float* out_w = (const float*)d_in[11];
    const float* out_b = (const float*)d_in[12];
    float* out = (float*)d_out;

    char* ws = (char*)d_ws;
    size_t off = 0;
    auto alloc = [&](size_t bytes) -> void* {
        void* p = ws + off;
        off += (bytes + 255) & ~(size_t)255;
        return p;
    };
    float* x            = (float*)alloc((size_t)N_NODES * HDIM * 4);
    unsigned short* xb  = (unsigned short*)alloc((size_t)N_NODES * HDIM * 2);
    unsigned short* P   = (unsigned short*)alloc((size_t)N_NODES * 512 * 2);
    unsigned short* Wp  = (unsigned short*)alloc((size_t)NLAYERS * 512 * 128 * 2);
    float* wfe          = (float*)alloc((size_t)NLAYERS * 128 * 4);
    float* wse          = (float*)alloc((size_t)NLAYERS * 128 * 4);
    int* deg            = (int*)alloc((size_t)N_NODES * 4);
    int* rowptr         = (int*)alloc((size_t)(N_NODES + 1) * 4);
    int* cursor         = (int*)alloc((size_t)N_NODES * 4);
    int* gstart         = (int*)alloc((size_t)(N_GRAPH + 1) * 4);
    int* bsum           = (int*)alloc((size_t)SCAN_BLOCKS * 4);
    int* boff           = (int*)alloc((size_t)SCAN_BLOCKS * 4);
    int2* csr           = (int2*)alloc((size_t)N_EDGES * 8);

    hipMemsetAsync(deg, 0, (size_t)N_NODES * 4, stream);

    k_embed_hist<<<(N_NODES * 32 + 255) / 256, 256, 0, stream>>>(atoms, embed, ei, x, xb, deg);
    k_scan1<<<SCAN_BLOCKS, 256, 0, stream>>>(deg, rowptr, bsum);
    k_scan2g<<<1, 256, 0, stream>>>(bsum, boff, rowptr, batch, gstart);
    k_scan3<<<SCAN_BLOCKS, 256, 0, stream>>>(boff, rowptr, cursor);
    k_scatter<<<(N_EDGES + 255) / 256, 256, 0, stream>>>(ei, pos, cursor, csr);
    k_pack<<<dim3(257, NLAYERS), 256, 0, stream>>>(lin_f_w, lin_s_w, Wp, wfe, wse);

    for (int l = 0; l < NLAYERS; ++l) {
        k_gemm<<<625, 512, 0, stream>>>(xb, Wp + (size_t)l * 512 * 128,
                                        lin_f_b + (size_t)l * HDIM,
                                        lin_s_b + (size_t)l * HDIM, P);
        k_edge_csr<<<N_NODES, 64, 0, stream>>>(P, wfe + (size_t)l * 128,
                                               wse + (size_t)l * 128, rowptr, csr,
                                               x, xb);
    }

    k_poolfc<<<N_GRAPH, 256, 0, stream>>>(x, gstart, fc_w, fc_b, out_w, out_b, out);
}

// Round 16
// 459.970 us; speedup vs baseline: 1.1519x; 1.0587x over previous
//
#include <hip/hip_runtime.h>
#include <cstdint>
#include <cstddef>

#define N_NODES 40000
#define N_EDGES 640000
#define N_GRAPH 256
#define HDIM 128
#define NLAYERS 5
#define ZDIM 257
#define SCAN_BLOCKS 157  // 157*256 = 40192 >= 40000
#define EP_STRIDE 520    // epilogue LDS row stride (ushorts): kills 4-way write conflict

typedef unsigned short ushort8_t __attribute__((ext_vector_type(8)));
typedef short short8 __attribute__((ext_vector_type(8)));
typedef float float4v __attribute__((ext_vector_type(4)));

static __device__ __forceinline__ float bf2f(unsigned short h) {
    return __uint_as_float((unsigned)h << 16);
}
static __device__ __forceinline__ unsigned short f2bf(float f) {
    unsigned u = __float_as_uint(f);
    unsigned r = u + 0x7fffu + ((u >> 16) & 1u);
    return (unsigned short)(r >> 16);
}

// ---------------- fused: embed gather + degree histogram ----------------
__global__ void k_embed_hist(const int* __restrict__ atoms, const float* __restrict__ embed,
                             const int* __restrict__ ei, float* __restrict__ x,
                             unsigned short* __restrict__ xb, int* __restrict__ deg) {
    int i = blockIdx.x * blockDim.x + threadIdx.x;
    if (i < N_NODES * 32) {
        int n = i >> 5, c = i & 31;
        int a = atoms[n];
        float4 v = ((const float4*)embed)[(size_t)a * 32 + c];
        ((float4*)x)[(size_t)n * 32 + c] = v;
        ushort4 w;
        w.x = f2bf(v.x); w.y = f2bf(v.y); w.z = f2bf(v.z); w.w = f2bf(v.w);
        ((ushort4*)xb)[(size_t)n * 32 + c] = w;
    }
    if (i < N_EDGES) {
        atomicAdd(&deg[ei[N_EDGES + i]], 1);
    }
}

// ---------------- 3-phase grid-wide exclusive scan ----------------
__global__ void k_scan1(const int* __restrict__ deg, int* __restrict__ rowptr,
                        int* __restrict__ bsum) {
    __shared__ int buf[256];
    int tid = threadIdx.x;
    int i = blockIdx.x * 256 + tid;
    int v = (i < N_NODES) ? deg[i] : 0;
    buf[tid] = v;
    __syncthreads();
    for (int off = 1; off < 256; off <<= 1) {
        int t = (tid >= off) ? buf[tid - off] : 0;
        __syncthreads();
        buf[tid] += t;
        __syncthreads();
    }
    if (i < N_NODES) rowptr[i] = buf[tid] - v;   // local exclusive
    if (tid == 255) bsum[blockIdx.x] = buf[255];
}

// phase 2 + graph boundaries (fused): one block does both
__global__ void k_scan2g(int* __restrict__ bsum, int* __restrict__ boff,
                         int* __restrict__ rowptr, const int* __restrict__ batch,
                         int* __restrict__ gstart) {
    __shared__ int buf[256];
    int tid = threadIdx.x;
    int v = (tid < SCAN_BLOCKS) ? bsum[tid] : 0;
    buf[tid] = v;
    __syncthreads();
    for (int off = 1; off < 256; off <<= 1) {
        int t = (tid >= off) ? buf[tid - off] : 0;
        __syncthreads();
        buf[tid] += t;
        __syncthreads();
    }
    if (tid < SCAN_BLOCKS) boff[tid] = buf[tid] - v;  // exclusive block offset
    if (tid == 255) rowptr[N_NODES] = buf[255];
    // gbound: g = tid (binary search sorted batch)
    {
        int g = tid;
        int lo = 0, hi = N_NODES;
        while (lo < hi) {
            int mid = (lo + hi) >> 1;
            if (batch[mid] < g) lo = mid + 1; else hi = mid;
        }
        gstart[g] = lo;
        if (tid == 0) gstart[N_GRAPH] = N_NODES;
    }
}

__global__ void k_scan3(const int* __restrict__ boff, int* __restrict__ rowptr,
                        int* __restrict__ cursor) {
    int i = blockIdx.x * 256 + threadIdx.x;
    if (i >= N_NODES) return;
    int e = rowptr[i] + boff[blockIdx.x];
    rowptr[i] = e;
    cursor[i] = e;
}

// ---------------- scatter edges into CSR (by dst), computing ea inline ----------------
__global__ void k_scatter(const int* __restrict__ ei, const float* __restrict__ pos,
                          int* __restrict__ cursor, int2* __restrict__ csr) {
    int e = blockIdx.x * 256 + threadIdx.x;
    if (e >= N_EDGES) return;
    int s = ei[e], d = ei[N_EDGES + e];
    float dx = pos[3 * s] - pos[3 * d];
    float dy = pos[3 * s + 1] - pos[3 * d + 1];
    float dz = pos[3 * s + 2] - pos[3 * d + 2];
    float ea = sqrtf(dx * dx + dy * dy + dz * dz);
    int p = atomicAdd(&cursor[d], 1);
    csr[p] = make_int2(s, __float_as_int(ea));
}

// ---------------- pack ALL 5 layers' weights -> Wp bf16 in MFMA-FRAGMENT order ----------------
// New layout: Wp[frag_id][lane][e], frag_id = (n>>4)*4 + ks (0..127), lane = l16 + 16*lg,
// e = 0..7. So a wave's B-fragment load (col-tile n>>4, k-step ks) is ONE contiguous 1 KB
// block: Wp + frag_id*512 + lane*8. Logical decode (n, k) -> source weight is unchanged:
//   n in [0,256): src block. t=n&3, ch=2*(n>>2)+(t&1). t<2 -> Wf[ch][128+k], else Ws[ch][128+k]
//   n in [256,512): dst block. cc=n-256, same decode. t<2 -> Wf[ch][k], else Ws[ch][k]
__global__ void k_pack(const float* __restrict__ lin_f_w, const float* __restrict__ lin_s_w,
                       unsigned short* __restrict__ Wp, float* __restrict__ wfe,
                       float* __restrict__ wse) {
    int l = blockIdx.y;
    const float* wf = lin_f_w + (size_t)l * HDIM * ZDIM;
    const float* ws = lin_s_w + (size_t)l * HDIM * ZDIM;
    unsigned short* Wpl = Wp + (size_t)l * 512 * 128;
    int i = blockIdx.x * 256 + threadIdx.x;
    if (i < 512 * 128) {
        int frag = i >> 9;               // 0..127
        int lane = (i >> 3) & 63;
        int e = i & 7;
        int fc = frag >> 2, ks = frag & 3;
        int l16 = lane & 15, lg = lane >> 4;
        int n = fc * 16 + l16;           // output column 0..511
        int k = ks * 32 + lg * 8 + e;    // k index 0..127
        int blk = n >> 8;                // 0 = src block, 1 = dst block
        int cc = n & 255;
        int t = cc & 3;
        int ch = 2 * (cc >> 2) + (t & 1);
        const float* W = (t < 2) ? wf : ws;
        int col = blk ? k : (128 + k);
        Wpl[i] = f2bf(W[ch * ZDIM + col]);
    } else if (i < 512 * 128 + 256) {
        int j = i - 512 * 128;
        if (j < 128) wfe[l * 128 + j] = wf[j * ZDIM + 256];
        else wse[l * 128 + (j - 128)] = ws[(j - 128) * ZDIM + 256];
    }
}

// ---------------- MFMA node GEMM (merged cols, fragment-ordered B): ----------------
// grid 625: 64-row tiles, 512 cols per block. 8 waves, wave w = cols [w*64,+64) x 64 rows.
// B-fragment loads are now single coalesced 1 KB wave transactions (was 16x 64 B scatter).
__launch_bounds__(512, 4)
__global__ void k_gemm(const unsigned short* __restrict__ xb,
                       const unsigned short* __restrict__ Wp,
                       const float* __restrict__ bf, const float* __restrict__ bs,
                       unsigned short* __restrict__ P) {
    __shared__ unsigned short smem[32 * EP_STRIDE];  // 32.5 KB; A tile uses first 16 KB
    unsigned short* A = smem;                        // A tile: 64 rows x 128 k
    const int row0 = blockIdx.x * 64;
    const int tid = threadIdx.x;

    {
        int r = tid >> 3, sub = tid & 7;
        const ushort8_t* src = (const ushort8_t*)(xb + (size_t)(row0 + r) * 128 + sub * 16);
        ushort8_t v0 = src[0], v1 = src[1];
        int h = r & 7;
        *(ushort8_t*)(A + r * 128 + (((sub * 2) ^ h) * 8)) = v0;
        *(ushort8_t*)(A + r * 128 + (((sub * 2 + 1) ^ h) * 8)) = v1;
    }
    __syncthreads();

    const int wid = tid >> 6, lane = tid & 63;
    const int l16 = lane & 15, lg = lane >> 4;

    float4v acc[4][4];
#pragma unroll
    for (int i = 0; i < 4; ++i)
#pragma unroll
        for (int j = 0; j < 4; ++j) acc[i][j] = (float4v){0.f, 0.f, 0.f, 0.f};

#pragma unroll
    for (int ks = 0; ks < 4; ++ks) {             // K = 128 in steps of 32
        short8 bfr[4];
#pragma unroll
        for (int cf = 0; cf < 4; ++cf) {
            int frag = (wid * 4 + cf) * 4 + ks;  // fragment-contiguous layout
            bfr[cf] = *(const short8*)(Wp + ((size_t)frag << 9) + lane * 8);
        }
#pragma unroll
        for (int rf = 0; rf < 4; ++rf) {
            int row = rf * 16 + l16;
            int kg = ks * 4 + lg;
            short8 af = *(const short8*)(A + row * 128 + ((kg ^ (row & 7)) * 8));
#pragma unroll
            for (int cf = 0; cf < 4; ++cf)
                acc[rf][cf] = __builtin_amdgcn_mfma_f32_16x16x32_bf16(
                    af, bfr[cf], acc[rf][cf], 0, 0, 0);
        }
    }

    float bias[4];
#pragma unroll
    for (int cf = 0; cf < 4; ++cf) {
        int n = wid * 64 + cf * 16 + l16;
        if (n < 256) bias[cf] = 0.f;
        else {
            int cc = n - 256;
            int t = cc & 3;
            int ch = 2 * (cc >> 2) + (t & 1);
            bias[cf] = (t < 2) ? bf[ch] : bs[ch];
        }
    }

#pragma unroll
    for (int p = 0; p < 2; ++p) {
        __syncthreads();
#pragma unroll
        for (int rfl = 0; rfl < 2; ++rfl) {
            int rf = 2 * p + rfl;
#pragma unroll
            for (int cf = 0; cf < 4; ++cf) {
                int col = wid * 64 + cf * 16 + l16;
#pragma unroll
                for (int r = 0; r < 4; ++r) {
                    int rowl = rfl * 16 + lg * 4 + r;     // 0..31
                    smem[rowl * EP_STRIDE + col] = f2bf(acc[rf][cf][r] + bias[cf]);
                }
            }
        }
        __syncthreads();
#pragma unroll
        for (int i = 0; i < 4; ++i) {
            int u = i * 512 + tid;
            int rw = u >> 6, ch = u & 63;
            *(ushort8_t*)(P + (size_t)(row0 + p * 32 + rw) * 512 + ch * 8) =
                *(const ushort8_t*)(smem + rw * EP_STRIDE + ch * 8);
        }
    }
}

// ---------------- CSR edge kernel: one wave per dst node, 4 edges in flight ----------------
__launch_bounds__(64)
__global__ void k_edge_csr(const unsigned short* __restrict__ P,
                           const float* __restrict__ wfe, const float* __restrict__ wse,
                           const int* __restrict__ rowptr, const int2* __restrict__ csr,
                           float* __restrict__ x, unsigned short* __restrict__ xb) {
    int node = blockIdx.x;
    int lane = threadIdx.x;
    int beg = rowptr[node], end = rowptr[node + 1];
    ushort4 dv = *(const ushort4*)(P + (size_t)node * 512 + 256 + 4 * lane);
    float fi0 = bf2f(dv.x), fi1 = bf2f(dv.y);
    float si0 = bf2f(dv.z), si1 = bf2f(dv.w);
    float2 wf = ((const float2*)wfe)[lane];
    float2 wsv = ((const float2*)wse)[lane];
    float acc0 = 0.f, acc1 = 0.f;
    const float LOG2E = 1.44269504f, LN2 = 0.69314718f;

    auto edge_math = [&](ushort4 sv, float eav) {
        float g0 = fi0 + bf2f(sv.x) + eav * wf.x;
        float g1 = fi1 + bf2f(sv.y) + eav * wf.y;
        float c0 = si0 + bf2f(sv.z) + eav * wsv.x;
        float c1 = si1 + bf2f(sv.w) + eav * wsv.y;
        float sg0 = __builtin_amdgcn_rcpf(1.f + __builtin_amdgcn_exp2f(-g0 * LOG2E));
        float sg1 = __builtin_amdgcn_rcpf(1.f + __builtin_amdgcn_exp2f(-g1 * LOG2E));
        float a0 = fabsf(c0), a1 = fabsf(c1);
        float l0 = __builtin_amdgcn_logf(1.f + __builtin_amdgcn_exp2f(-a0 * LOG2E)) * LN2;
        float l1 = __builtin_amdgcn_logf(1.f + __builtin_amdgcn_exp2f(-a1 * LOG2E)) * LN2;
        float sp0 = fmaxf(c0, 0.f) + l0;
        float sp1 = fmaxf(c1, 0.f) + l1;
        acc0 += sg0 * sp0;
        acc1 += sg1 * sp1;
    };

    int e = beg;
    for (; e + 4 <= end; e += 4) {
        int2 c0 = csr[e];
        int2 c1 = csr[e + 1];
        int2 c2 = csr[e + 2];
        int2 c3 = csr[e + 3];
        int s0 = __builtin_amdgcn_readfirstlane(c0.x);
        float ea0 = __uint_as_float(__builtin_amdgcn_readfirstlane((unsigned)c0.y));
        int s1 = __builtin_amdgcn_readfirstlane(c1.x);
        float ea1 = __uint_as_float(__builtin_amdgcn_readfirstlane((unsigned)c1.y));
        int s2 = __builtin_amdgcn_readfirstlane(c2.x);
        float ea2 = __uint_as_float(__builtin_amdgcn_readfirstlane((unsigned)c2.y));
        int s3 = __builtin_amdgcn_readfirstlane(c3.x);
        float ea3 = __uint_as_float(__builtin_amdgcn_readfirstlane((unsigned)c3.y));
        ushort4 sv0 = *(const ushort4*)(P + (size_t)s0 * 512 + 4 * lane);
        ushort4 sv1 = *(const ushort4*)(P + (size_t)s1 * 512 + 4 * lane);
        ushort4 sv2 = *(const ushort4*)(P + (size_t)s2 * 512 + 4 * lane);
        ushort4 sv3 = *(const ushort4*)(P + (size_t)s3 * 512 + 4 * lane);
        edge_math(sv0, ea0);
        edge_math(sv1, ea1);
        edge_math(sv2, ea2);
        edge_math(sv3, ea3);
    }
    for (; e < end; ++e) {
        int2 c0 = csr[e];
        int s0 = __builtin_amdgcn_readfirstlane(c0.x);
        float ea0 = __uint_as_float(__builtin_amdgcn_readfirstlane((unsigned)c0.y));
        ushort4 sv0 = *(const ushort4*)(P + (size_t)s0 * 512 + 4 * lane);
        edge_math(sv0, ea0);
    }

    float2* xd = (float2*)(x + (size_t)node * 128) + lane;
    float2 xv = *xd;
    xv.x += acc0;
    xv.y += acc1;
    *xd = xv;
    ushort2 xbv;
    xbv.x = f2bf(xv.x);
    xbv.y = f2bf(xv.y);
    ((ushort2*)(xb + (size_t)node * 128))[lane] = xbv;
}

// ---------------- fused mean-pool (2-way node-parallel) + FC head ----------------
__launch_bounds__(256)
__global__ void k_poolfc(const float* __restrict__ x, const int* __restrict__ gstart,
                         const float* __restrict__ fc_w, const float* __restrict__ fc_b,
                         const float* __restrict__ out_w, const float* __restrict__ out_b,
                         float* __restrict__ out) {
    int g = blockIdx.x;
    int tid = threadIdx.x;
    int h = tid & 127;
    int half = tid >> 7;                 // 0: even nodes, 1: odd nodes
    int s = gstart[g], e = gstart[g + 1];
    float sum = 0.f;
    for (int n = s + half; n < e; n += 2) sum += x[(size_t)n * HDIM + h];
    __shared__ float part[256];
    __shared__ float gin[128];
    __shared__ float gout[128];
    part[tid] = sum;
    __syncthreads();
    float cnt = fmaxf((float)(e - s), 1.0f);
    if (tid < 128) gin[h] = (part[h] + part[h + 128]) / cnt;
    __syncthreads();
    for (int l = 0; l < 3; ++l) {
        float acc = 0.f;
        if (tid < 128) {
            const float* W = fc_w + (size_t)l * HDIM * HDIM + (size_t)h * HDIM;
            acc = fc_b[l * HDIM + h];
#pragma unroll 4
            for (int k = 0; k < HDIM; k += 4) {
                float4 w4 = *(const float4*)(W + k);
                acc += gin[k] * w4.x + gin[k + 1] * w4.y + gin[k + 2] * w4.z + gin[k + 3] * w4.w;
            }
        }
        __syncthreads();
        if (tid < 128) gout[h] = acc;
        __syncthreads();
        if (tid < 128) gin[h] = gout[h];
        __syncthreads();
    }
    if (tid < 128) gout[h] = gin[h] * out_w[h];
    __syncthreads();
    if (tid < 64) gout[tid] += gout[tid + 64];
    __syncthreads();
    if (tid == 0) {
        float acc = 0.f;
        for (int i = 0; i < 64; ++i) acc += gout[i];
        out[g] = acc + out_b[0];
    }
}

extern "C" void kernel_launch(void* const* d_in, const int* in_sizes, int n_in,
                              void* d_out, int out_size, void* d_ws, size_t ws_size,
                              hipStream_t stream) {
    const int* atoms = (const int*)d_in[0];
    const float* pos = (const float*)d_in[1];
    const int* ei = (const int*)d_in[2];
    const int* batch = (const int*)d_in[3];
    const float* embed = (const float*)d_in[4];
    const float* lin_f_w = (const float*)d_in[5];
    const float* lin_f_b = (const float*)d_in[6];
    const float* lin_s_w = (const float*)d_in[7];
    const float* lin_s_b = (const float*)d_in[8];
    const float* fc_w = (const float*)d_in[9];
    const float* fc_b = (const float*)d_in[10];
    const float* out_w = (const float*)d_in[11];
    const float* out_b = (const float*)d_in[12];
    float* out = (float*)d_out;

    char* ws = (char*)d_ws;
    size_t off = 0;
    auto alloc = [&](size_t bytes) -> void* {
        void* p = ws + off;
        off += (bytes + 255) & ~(size_t)255;
        return p;
    };
    float* x            = (float*)alloc((size_t)N_NODES * HDIM * 4);
    unsigned short* xb  = (unsigned short*)alloc((size_t)N_NODES * HDIM * 2);
    unsigned short* P   = (unsigned short*)alloc((size_t)N_NODES * 512 * 2);
    unsigned short* Wp  = (unsigned short*)alloc((size_t)NLAYERS * 512 * 128 * 2);
    float* wfe          = (float*)alloc((size_t)NLAYERS * 128 * 4);
    float* wse          = (float*)alloc((size_t)NLAYERS * 128 * 4);
    int* deg            = (int*)alloc((size_t)N_NODES * 4);
    int* rowptr         = (int*)alloc((size_t)(N_NODES + 1) * 4);
    int* cursor         = (int*)alloc((size_t)N_NODES * 4);
    int* gstart         = (int*)alloc((size_t)(N_GRAPH + 1) * 4);
    int* bsum           = (int*)alloc((size_t)SCAN_BLOCKS * 4);
    int* boff           = (int*)alloc((size_t)SCAN_BLOCKS * 4);
    int2* csr           = (int2*)alloc((size_t)N_EDGES * 8);

    hipMemsetAsync(deg, 0, (size_t)N_NODES * 4, stream);

    k_embed_hist<<<(N_NODES * 32 + 255) / 256, 256, 0, stream>>>(atoms, embed, ei, x, xb, deg);
    k_scan1<<<SCAN_BLOCKS, 256, 0, stream>>>(deg, rowptr, bsum);
    k_scan2g<<<1, 256, 0, stream>>>(bsum, boff, rowptr, batch, gstart);
    k_scan3<<<SCAN_BLOCKS, 256, 0, stream>>>(boff, rowptr, cursor);
    k_scatter<<<(N_EDGES + 255) / 256, 256, 0, stream>>>(ei, pos, cursor, csr);
    k_pack<<<dim3(257, NLAYERS), 256, 0, stream>>>(lin_f_w, lin_s_w, Wp, wfe, wse);

    for (int l = 0; l < NLAYERS; ++l) {
        k_gemm<<<625, 512, 0, stream>>>(xb, Wp + (size_t)l * 512 * 128,
                                        lin_f_b + (size_t)l * HDIM,
                                        lin_s_b + (size_t)l * HDIM, P);
        k_edge_csr<<<N_NODES, 64, 0, stream>>>(P, wfe + (size_t)l * 128,
                                               wse + (size_t)l * 128, rowptr, csr,
                                               x, xb);
    }

    k_poolfc<<<N_GRAPH, 256, 0, stream>>>(x, gstart, fc_w, fc_b, out_w, out_b, out);
}

// Round 17
// 448.936 us; speedup vs baseline: 1.1802x; 1.0246x over previous
//
#include <hip/hip_runtime.h>
#include <cstdint>
#include <cstddef>

#define N_NODES 40000
#define N_EDGES 640000
#define N_GRAPH 256
#define HDIM 128
#define NLAYERS 5
#define ZDIM 257
#define SCAN_BLOCKS 157  // 157*256 = 40192 >= 40000
#define EP_STRIDE 520    // epilogue LDS row stride (ushorts): kills 4-way write conflict

typedef unsigned short ushort8_t __attribute__((ext_vector_type(8)));
typedef short short8 __attribute__((ext_vector_type(8)));
typedef float float4v __attribute__((ext_vector_type(4)));

static __device__ __forceinline__ float bf2f(unsigned short h) {
    return __uint_as_float((unsigned)h << 16);
}
static __device__ __forceinline__ unsigned short f2bf(float f) {
    unsigned u = __float_as_uint(f);
    unsigned r = u + 0x7fffu + ((u >> 16) & 1u);
    return (unsigned short)(r >> 16);
}

// ---------------- fused: embed gather + degree histogram ----------------
__global__ void k_embed_hist(const int* __restrict__ atoms, const float* __restrict__ embed,
                             const int* __restrict__ ei, float* __restrict__ x,
                             unsigned short* __restrict__ xb, int* __restrict__ deg) {
    int i = blockIdx.x * blockDim.x + threadIdx.x;
    if (i < N_NODES * 32) {
        int n = i >> 5, c = i & 31;
        int a = atoms[n];
        float4 v = ((const float4*)embed)[(size_t)a * 32 + c];
        ((float4*)x)[(size_t)n * 32 + c] = v;
        ushort4 w;
        w.x = f2bf(v.x); w.y = f2bf(v.y); w.z = f2bf(v.z); w.w = f2bf(v.w);
        ((ushort4*)xb)[(size_t)n * 32 + c] = w;
    }
    if (i < N_EDGES) {
        atomicAdd(&deg[ei[N_EDGES + i]], 1);
    }
}

// ---------------- 3-phase grid-wide exclusive scan ----------------
__global__ void k_scan1(const int* __restrict__ deg, int* __restrict__ rowptr,
                        int* __restrict__ bsum) {
    __shared__ int buf[256];
    int tid = threadIdx.x;
    int i = blockIdx.x * 256 + tid;
    int v = (i < N_NODES) ? deg[i] : 0;
    buf[tid] = v;
    __syncthreads();
    for (int off = 1; off < 256; off <<= 1) {
        int t = (tid >= off) ? buf[tid - off] : 0;
        __syncthreads();
        buf[tid] += t;
        __syncthreads();
    }
    if (i < N_NODES) rowptr[i] = buf[tid] - v;   // local exclusive
    if (tid == 255) bsum[blockIdx.x] = buf[255];
}

// phase 2 + graph boundaries (fused): one block does both
__global__ void k_scan2g(int* __restrict__ bsum, int* __restrict__ boff,
                         int* __restrict__ rowptr, const int* __restrict__ batch,
                         int* __restrict__ gstart) {
    __shared__ int buf[256];
    int tid = threadIdx.x;
    int v = (tid < SCAN_BLOCKS) ? bsum[tid] : 0;
    buf[tid] = v;
    __syncthreads();
    for (int off = 1; off < 256; off <<= 1) {
        int t = (tid >= off) ? buf[tid - off] : 0;
        __syncthreads();
        buf[tid] += t;
        __syncthreads();
    }
    if (tid < SCAN_BLOCKS) boff[tid] = buf[tid] - v;  // exclusive block offset
    if (tid == 255) rowptr[N_NODES] = buf[255];
    {
        int g = tid;
        int lo = 0, hi = N_NODES;
        while (lo < hi) {
            int mid = (lo + hi) >> 1;
            if (batch[mid] < g) lo = mid + 1; else hi = mid;
        }
        gstart[g] = lo;
        if (tid == 0) gstart[N_GRAPH] = N_NODES;
    }
}

__global__ void k_scan3(const int* __restrict__ boff, int* __restrict__ rowptr,
                        int* __restrict__ cursor) {
    int i = blockIdx.x * 256 + threadIdx.x;
    if (i >= N_NODES) return;
    int e = rowptr[i] + boff[blockIdx.x];
    rowptr[i] = e;
    cursor[i] = e;
}

// ---------------- scatter edges into CSR (by dst), computing ea inline ----------------
__global__ void k_scatter(const int* __restrict__ ei, const float* __restrict__ pos,
                          int* __restrict__ cursor, int2* __restrict__ csr) {
    int e = blockIdx.x * 256 + threadIdx.x;
    if (e >= N_EDGES) return;
    int s = ei[e], d = ei[N_EDGES + e];
    float dx = pos[3 * s] - pos[3 * d];
    float dy = pos[3 * s + 1] - pos[3 * d + 1];
    float dz = pos[3 * s + 2] - pos[3 * d + 2];
    float ea = sqrtf(dx * dx + dy * dy + dz * dz);
    int p = atomicAdd(&cursor[d], 1);
    csr[p] = make_int2(s, __float_as_int(ea));
}

// ---------------- pack ALL 5 layers' weights -> Wp bf16 in MFMA-FRAGMENT order ----------------
// Wp[frag_id][lane][e], frag_id = (n>>4)*4 + ks, lane = l16 + 16*lg, e = 0..7.
__global__ void k_pack(const float* __restrict__ lin_f_w, const float* __restrict__ lin_s_w,
                       unsigned short* __restrict__ Wp, float* __restrict__ wfe,
                       float* __restrict__ wse) {
    int l = blockIdx.y;
    const float* wf = lin_f_w + (size_t)l * HDIM * ZDIM;
    const float* ws = lin_s_w + (size_t)l * HDIM * ZDIM;
    unsigned short* Wpl = Wp + (size_t)l * 512 * 128;
    int i = blockIdx.x * 256 + threadIdx.x;
    if (i < 512 * 128) {
        int frag = i >> 9;               // 0..127
        int lane = (i >> 3) & 63;
        int e = i & 7;
        int fc = frag >> 2, ks = frag & 3;
        int l16 = lane & 15, lg = lane >> 4;
        int n = fc * 16 + l16;           // output column 0..511
        int k = ks * 32 + lg * 8 + e;    // k index 0..127
        int blk = n >> 8;                // 0 = src block, 1 = dst block
        int cc = n & 255;
        int t = cc & 3;
        int ch = 2 * (cc >> 2) + (t & 1);
        const float* W = (t < 2) ? wf : ws;
        int col = blk ? k : (128 + k);
        Wpl[i] = f2bf(W[ch * ZDIM + col]);
    } else if (i < 512 * 128 + 256) {
        int j = i - 512 * 128;
        if (j < 128) wfe[l * 128 + j] = wf[j * ZDIM + 256];
        else wse[l * 128 + (j - 128)] = ws[(j - 128) * ZDIM + 256];
    }
}

// ---------------- MFMA node GEMM (merged cols, fragment-ordered B) ----------------
__launch_bounds__(512, 4)
__global__ void k_gemm(const unsigned short* __restrict__ xb,
                       const unsigned short* __restrict__ Wp,
                       const float* __restrict__ bf, const float* __restrict__ bs,
                       unsigned short* __restrict__ P) {
    __shared__ unsigned short smem[32 * EP_STRIDE];  // 32.5 KB; A tile uses first 16 KB
    unsigned short* A = smem;                        // A tile: 64 rows x 128 k
    const int row0 = blockIdx.x * 64;
    const int tid = threadIdx.x;

    {
        int r = tid >> 3, sub = tid & 7;
        const ushort8_t* src = (const ushort8_t*)(xb + (size_t)(row0 + r) * 128 + sub * 16);
        ushort8_t v0 = src[0], v1 = src[1];
        int h = r & 7;
        *(ushort8_t*)(A + r * 128 + (((sub * 2) ^ h) * 8)) = v0;
        *(ushort8_t*)(A + r * 128 + (((sub * 2 + 1) ^ h) * 8)) = v1;
    }
    __syncthreads();

    const int wid = tid >> 6, lane = tid & 63;
    const int l16 = lane & 15, lg = lane >> 4;

    float4v acc[4][4];
#pragma unroll
    for (int i = 0; i < 4; ++i)
#pragma unroll
        for (int j = 0; j < 4; ++j) acc[i][j] = (float4v){0.f, 0.f, 0.f, 0.f};

#pragma unroll
    for (int ks = 0; ks < 4; ++ks) {             // K = 128 in steps of 32
        short8 bfr[4];
#pragma unroll
        for (int cf = 0; cf < 4; ++cf) {
            int frag = (wid * 4 + cf) * 4 + ks;  // fragment-contiguous layout
            bfr[cf] = *(const short8*)(Wp + ((size_t)frag << 9) + lane * 8);
        }
#pragma unroll
        for (int rf = 0; rf < 4; ++rf) {
            int row = rf * 16 + l16;
            int kg = ks * 4 + lg;
            short8 af = *(const short8*)(A + row * 128 + ((kg ^ (row & 7)) * 8));
#pragma unroll
            for (int cf = 0; cf < 4; ++cf)
                acc[rf][cf] = __builtin_amdgcn_mfma_f32_16x16x32_bf16(
                    af, bfr[cf], acc[rf][cf], 0, 0, 0);
        }
    }

    float bias[4];
#pragma unroll
    for (int cf = 0; cf < 4; ++cf) {
        int n = wid * 64 + cf * 16 + l16;
        if (n < 256) bias[cf] = 0.f;
        else {
            int cc = n - 256;
            int t = cc & 3;
            int ch = 2 * (cc >> 2) + (t & 1);
            bias[cf] = (t < 2) ? bf[ch] : bs[ch];
        }
    }

#pragma unroll
    for (int p = 0; p < 2; ++p) {
        __syncthreads();
#pragma unroll
        for (int rfl = 0; rfl < 2; ++rfl) {
            int rf = 2 * p + rfl;
#pragma unroll
            for (int cf = 0; cf < 4; ++cf) {
                int col = wid * 64 + cf * 16 + l16;
#pragma unroll
                for (int r = 0; r < 4; ++r) {
                    int rowl = rfl * 16 + lg * 4 + r;     // 0..31
                    smem[rowl * EP_STRIDE + col] = f2bf(acc[rf][cf][r] + bias[cf]);
                }
            }
        }
        __syncthreads();
#pragma unroll
        for (int i = 0; i < 4; ++i) {
            int u = i * 512 + tid;
            int rw = u >> 6, ch = u & 63;
            *(ushort8_t*)(P + (size_t)(row0 + p * 32 + rw) * 512 + ch * 8) =
                *(const ushort8_t*)(smem + rw * EP_STRIDE + ch * 8);
        }
    }
}

// ---------------- CSR edge kernel: one wave per dst node, 2-deep pipelined 4-edge batches ----------------
__launch_bounds__(64)
__global__ void k_edge_csr(const unsigned short* __restrict__ P,
                           const float* __restrict__ wfe, const float* __restrict__ wse,
                           const int* __restrict__ rowptr, const int2* __restrict__ csr,
                           float* __restrict__ x, unsigned short* __restrict__ xb) {
    int node = blockIdx.x;
    int lane = threadIdx.x;
    int beg = rowptr[node], end = rowptr[node + 1];
    ushort4 dv = *(const ushort4*)(P + (size_t)node * 512 + 256 + 4 * lane);
    float fi0 = bf2f(dv.x), fi1 = bf2f(dv.y);
    float si0 = bf2f(dv.z), si1 = bf2f(dv.w);
    float2 wf = ((const float2*)wfe)[lane];
    float2 wsv = ((const float2*)wse)[lane];
    float acc0 = 0.f, acc1 = 0.f;
    const float LOG2E = 1.44269504f, LN2 = 0.69314718f;

    auto edge_math = [&](ushort4 sv, float eav) {
        float g0 = fi0 + bf2f(sv.x) + eav * wf.x;
        float g1 = fi1 + bf2f(sv.y) + eav * wf.y;
        float c0 = si0 + bf2f(sv.z) + eav * wsv.x;
        float c1 = si1 + bf2f(sv.w) + eav * wsv.y;
        float sg0 = __builtin_amdgcn_rcpf(1.f + __builtin_amdgcn_exp2f(-g0 * LOG2E));
        float sg1 = __builtin_amdgcn_rcpf(1.f + __builtin_amdgcn_exp2f(-g1 * LOG2E));
        float a0 = fabsf(c0), a1 = fabsf(c1);
        float l0 = __builtin_amdgcn_logf(1.f + __builtin_amdgcn_exp2f(-a0 * LOG2E)) * LN2;
        float l1 = __builtin_amdgcn_logf(1.f + __builtin_amdgcn_exp2f(-a1 * LOG2E)) * LN2;
        float sp0 = fmaxf(c0, 0.f) + l0;
        float sp1 = fmaxf(c1, 0.f) + l1;
        acc0 += sg0 * sp0;
        acc1 += sg1 * sp1;
    };

    auto load4 = [&](int eb, ushort4 (&sv)[4], float (&ea)[4]) {
#pragma unroll
        for (int i = 0; i < 4; ++i) {
            int2 c = csr[eb + i];
            int s = __builtin_amdgcn_readfirstlane(c.x);
            ea[i] = __uint_as_float(__builtin_amdgcn_readfirstlane((unsigned)c.y));
            sv[i] = *(const ushort4*)(P + (size_t)s * 512 + 4 * lane);
        }
    };

    int nb = (end - beg) >> 2;           // full 4-edge batches
    int e = beg + (nb << 2);
    if (nb > 0) {
        ushort4 sv0[4]; float ea0[4];
        load4(beg, sv0, ea0);
        for (int b = 1; b < nb; ++b) {
            ushort4 sv1[4]; float ea1[4];
            load4(beg + (b << 2), sv1, ea1);   // issue next batch's loads...
#pragma unroll
            for (int i = 0; i < 4; ++i) edge_math(sv0[i], ea0[i]);  // ...hidden under this math
#pragma unroll
            for (int i = 0; i < 4; ++i) { sv0[i] = sv1[i]; ea0[i] = ea1[i]; }
        }
#pragma unroll
        for (int i = 0; i < 4; ++i) edge_math(sv0[i], ea0[i]);
    }
    for (; e < end; ++e) {
        int2 c0 = csr[e];
        int s0 = __builtin_amdgcn_readfirstlane(c0.x);
        float ea0 = __uint_as_float(__builtin_amdgcn_readfirstlane((unsigned)c0.y));
        ushort4 sv0 = *(const ushort4*)(P + (size_t)s0 * 512 + 4 * lane);
        edge_math(sv0, ea0);
    }

    float2* xd = (float2*)(x + (size_t)node * 128) + lane;
    float2 xv = *xd;
    xv.x += acc0;
    xv.y += acc1;
    *xd = xv;
    ushort2 xbv;
    xbv.x = f2bf(xv.x);
    xbv.y = f2bf(xv.y);
    ((ushort2*)(xb + (size_t)node * 128))[lane] = xbv;
}

// ---------------- fused mean-pool (4-way node-parallel) + FC head ----------------
__launch_bounds__(512)
__global__ void k_poolfc(const float* __restrict__ x, const int* __restrict__ gstart,
                         const float* __restrict__ fc_w, const float* __restrict__ fc_b,
                         const float* __restrict__ out_w, const float* __restrict__ out_b,
                         float* __restrict__ out) {
    int g = blockIdx.x;
    int tid = threadIdx.x;
    int h = tid & 127;
    int q = tid >> 7;                    // 0..3: node-quarter
    int s = gstart[g], e = gstart[g + 1];
    float sum = 0.f;
    for (int n = s + q; n < e; n += 4) sum += x[(size_t)n * HDIM + h];
    __shared__ float part[512];
    __shared__ float gin[128];
    __shared__ float gout[128];
    part[tid] = sum;
    __syncthreads();
    float cnt = fmaxf((float)(e - s), 1.0f);
    if (tid < 128) gin[h] = (part[h] + part[h + 128] + part[h + 256] + part[h + 384]) / cnt;
    __syncthreads();
    for (int l = 0; l < 3; ++l) {
        float acc = 0.f;
        if (tid < 128) {
            const float* W = fc_w + (size_t)l * HDIM * HDIM + (size_t)h * HDIM;
            acc = fc_b[l * HDIM + h];
#pragma unroll 4
            for (int k = 0; k < HDIM; k += 4) {
                float4 w4 = *(const float4*)(W + k);
                acc += gin[k] * w4.x + gin[k + 1] * w4.y + gin[k + 2] * w4.z + gin[k + 3] * w4.w;
            }
        }
        __syncthreads();
        if (tid < 128) gout[h] = acc;
        __syncthreads();
        if (tid < 128) gin[h] = gout[h];
        __syncthreads();
    }
    if (tid < 128) gout[h] = gin[h] * out_w[h];
    __syncthreads();
    if (tid < 64) gout[tid] += gout[tid + 64];
    __syncthreads();
    if (tid == 0) {
        float acc = 0.f;
        for (int i = 0; i < 64; ++i) acc += gout[i];
        out[g] = acc + out_b[0];
    }
}

extern "C" void kernel_launch(void* const* d_in, const int* in_sizes, int n_in,
                              void* d_out, int out_size, void* d_ws, size_t ws_size,
                              hipStream_t stream) {
    const int* atoms = (const int*)d_in[0];
    const float* pos = (const float*)d_in[1];
    const int* ei = (const int*)d_in[2];
    const int* batch = (const int*)d_in[3];
    const float* embed = (const float*)d_in[4];
    const float* lin_f_w = (const float*)d_in[5];
    const float* lin_f_b = (const float*)d_in[6];
    const float* lin_s_w = (const float*)d_in[7];
    const float* lin_s_b = (const float*)d_in[8];
    const float* fc_w = (const float*)d_in[9];
    const float* fc_b = (const float*)d_in[10];
    const float* out_w = (const float*)d_in[11];
    const float* out_b = (const float*)d_in[12];
    float* out = (float*)d_out;

    char* ws = (char*)d_ws;
    size_t off = 0;
    auto alloc = [&](size_t bytes) -> void* {
        void* p = ws + off;
        off += (bytes + 255) & ~(size_t)255;
        return p;
    };
    float* x            = (float*)alloc((size_t)N_NODES * HDIM * 4);
    unsigned short* xb  = (unsigned short*)alloc((size_t)N_NODES * HDIM * 2);
    unsigned short* P   = (unsigned short*)alloc((size_t)N_NODES * 512 * 2);
    unsigned short* Wp  = (unsigned short*)alloc((size_t)NLAYERS * 512 * 128 * 2);
    float* wfe          = (float*)alloc((size_t)NLAYERS * 128 * 4);
    float* wse          = (float*)alloc((size_t)NLAYERS * 128 * 4);
    int* deg            = (int*)alloc((size_t)N_NODES * 4);
    int* rowptr         = (int*)alloc((size_t)(N_NODES + 1) * 4);
    int* cursor         = (int*)alloc((size_t)N_NODES * 4);
    int* gstart         = (int*)alloc((size_t)(N_GRAPH + 1) * 4);
    int* bsum           = (int*)alloc((size_t)SCAN_BLOCKS * 4);
    int* boff           = (int*)alloc((size_t)SCAN_BLOCKS * 4);
    int2* csr           = (int2*)alloc((size_t)N_EDGES * 8);

    hipMemsetAsync(deg, 0, (size_t)N_NODES * 4, stream);

    k_embed_hist<<<(N_NODES * 32 + 255) / 256, 256, 0, stream>>>(atoms, embed, ei, x, xb, deg);
    k_scan1<<<SCAN_BLOCKS, 256, 0, stream>>>(deg, rowptr, bsum);
    k_scan2g<<<1, 256, 0, stream>>>(bsum, boff, rowptr, batch, gstart);
    k_scan3<<<SCAN_BLOCKS, 256, 0, stream>>>(boff, rowptr, cursor);
    k_scatter<<<(N_EDGES + 255) / 256, 256, 0, stream>>>(ei, pos, cursor, csr);
    k_pack<<<dim3(257, NLAYERS), 256, 0, stream>>>(lin_f_w, lin_s_w, Wp, wfe, wse);

    for (int l = 0; l < NLAYERS; ++l) {
        k_gemm<<<625, 512, 0, stream>>>(xb, Wp + (size_t)l * 512 * 128,
                                        lin_f_b + (size_t)l * HDIM,
                                        lin_s_b + (size_t)l * HDIM, P);
        k_edge_csr<<<N_NODES, 64, 0, stream>>>(P, wfe + (size_t)l * 128,
                                               wse + (size_t)l * 128, rowptr, csr,
                                               x, xb);
    }

    k_poolfc<<<N_GRAPH, 512, 0, stream>>>(x, gstart, fc_w, fc_b, out_w, out_b, out);
}

// Round 18
// 448.803 us; speedup vs baseline: 1.1805x; 1.0003x over previous
//
#include <hip/hip_runtime.h>
#include <cstdint>
#include <cstddef>

#define N_NODES 40000
#define N_EDGES 640000
#define N_GRAPH 256
#define HDIM 128
#define NLAYERS 5
#define ZDIM 257
#define SCAN_BLOCKS 157  // 157*256 = 40192 >= 40000
#define EP_STRIDE 520    // epilogue LDS row stride (ushorts): kills 4-way write conflict
#define LOG2E_F 1.44269504f
#define LN2_F 0.69314718f

typedef unsigned short ushort8_t __attribute__((ext_vector_type(8)));
typedef short short8 __attribute__((ext_vector_type(8)));
typedef float float4v __attribute__((ext_vector_type(4)));

static __device__ __forceinline__ float bf2f(unsigned short h) {
    return __uint_as_float((unsigned)h << 16);
}
static __device__ __forceinline__ unsigned short f2bf(float f) {
    unsigned u = __float_as_uint(f);
    unsigned r = u + 0x7fffu + ((u >> 16) & 1u);
    return (unsigned short)(r >> 16);
}

// ---------------- fused: embed gather + degree histogram ----------------
__global__ void k_embed_hist(const int* __restrict__ atoms, const float* __restrict__ embed,
                             const int* __restrict__ ei, float* __restrict__ x,
                             unsigned short* __restrict__ xb, int* __restrict__ deg) {
    int i = blockIdx.x * blockDim.x + threadIdx.x;
    if (i < N_NODES * 32) {
        int n = i >> 5, c = i & 31;
        int a = atoms[n];
        float4 v = ((const float4*)embed)[(size_t)a * 32 + c];
        ((float4*)x)[(size_t)n * 32 + c] = v;
        ushort4 w;
        w.x = f2bf(v.x); w.y = f2bf(v.y); w.z = f2bf(v.z); w.w = f2bf(v.w);
        ((ushort4*)xb)[(size_t)n * 32 + c] = w;
    }
    if (i < N_EDGES) {
        atomicAdd(&deg[ei[N_EDGES + i]], 1);
    }
}

// ---------------- 3-phase grid-wide exclusive scan ----------------
__global__ void k_scan1(const int* __restrict__ deg, int* __restrict__ rowptr,
                        int* __restrict__ bsum) {
    __shared__ int buf[256];
    int tid = threadIdx.x;
    int i = blockIdx.x * 256 + tid;
    int v = (i < N_NODES) ? deg[i] : 0;
    buf[tid] = v;
    __syncthreads();
    for (int off = 1; off < 256; off <<= 1) {
        int t = (tid >= off) ? buf[tid - off] : 0;
        __syncthreads();
        buf[tid] += t;
        __syncthreads();
    }
    if (i < N_NODES) rowptr[i] = buf[tid] - v;   // local exclusive
    if (tid == 255) bsum[blockIdx.x] = buf[255];
}

// phase 2 + graph boundaries (fused): one block does both
__global__ void k_scan2g(int* __restrict__ bsum, int* __restrict__ boff,
                         int* __restrict__ rowptr, const int* __restrict__ batch,
                         int* __restrict__ gstart) {
    __shared__ int buf[256];
    int tid = threadIdx.x;
    int v = (tid < SCAN_BLOCKS) ? bsum[tid] : 0;
    buf[tid] = v;
    __syncthreads();
    for (int off = 1; off < 256; off <<= 1) {
        int t = (tid >= off) ? buf[tid - off] : 0;
        __syncthreads();
        buf[tid] += t;
        __syncthreads();
    }
    if (tid < SCAN_BLOCKS) boff[tid] = buf[tid] - v;  // exclusive block offset
    if (tid == 255) rowptr[N_NODES] = buf[255];
    {
        int g = tid;
        int lo = 0, hi = N_NODES;
        while (lo < hi) {
            int mid = (lo + hi) >> 1;
            if (batch[mid] < g) lo = mid + 1; else hi = mid;
        }
        gstart[g] = lo;
        if (tid == 0) gstart[N_GRAPH] = N_NODES;
    }
}

__global__ void k_scan3(const int* __restrict__ boff, int* __restrict__ rowptr,
                        int* __restrict__ cursor) {
    int i = blockIdx.x * 256 + threadIdx.x;
    if (i >= N_NODES) return;
    int e = rowptr[i] + boff[blockIdx.x];
    rowptr[i] = e;
    cursor[i] = e;
}

// ---------------- scatter edges into CSR (by dst), computing ea inline ----------------
__global__ void k_scatter(const int* __restrict__ ei, const float* __restrict__ pos,
                          int* __restrict__ cursor, int2* __restrict__ csr) {
    int e = blockIdx.x * 256 + threadIdx.x;
    if (e >= N_EDGES) return;
    int s = ei[e], d = ei[N_EDGES + e];
    float dx = pos[3 * s] - pos[3 * d];
    float dy = pos[3 * s + 1] - pos[3 * d + 1];
    float dz = pos[3 * s + 2] - pos[3 * d + 2];
    float ea = sqrtf(dx * dx + dy * dy + dz * dz);
    int p = atomicAdd(&cursor[d], 1);
    csr[p] = make_int2(s, __float_as_int(ea));
}

// ---------------- pack ALL 5 layers' weights -> Wp bf16 in MFMA-FRAGMENT order ----------------
// Wp[frag_id][lane][e], frag_id = (n>>4)*4 + ks, lane = l16 + 16*lg, e = 0..7.
// wfe/wse pre-scaled by LOG2E in f32 (exact; weights themselves stay unscaled bf16 —
// the LOG2E scale for P happens in k_gemm's f32 epilogue, preserving single-rounding).
__global__ void k_pack(const float* __restrict__ lin_f_w, const float* __restrict__ lin_s_w,
                       unsigned short* __restrict__ Wp, float* __restrict__ wfe,
                       float* __restrict__ wse) {
    int l = blockIdx.y;
    const float* wf = lin_f_w + (size_t)l * HDIM * ZDIM;
    const float* ws = lin_s_w + (size_t)l * HDIM * ZDIM;
    unsigned short* Wpl = Wp + (size_t)l * 512 * 128;
    int i = blockIdx.x * 256 + threadIdx.x;
    if (i < 512 * 128) {
        int frag = i >> 9;               // 0..127
        int lane = (i >> 3) & 63;
        int e = i & 7;
        int fc = frag >> 2, ks = frag & 3;
        int l16 = lane & 15, lg = lane >> 4;
        int n = fc * 16 + l16;           // output column 0..511
        int k = ks * 32 + lg * 8 + e;    // k index 0..127
        int blk = n >> 8;                // 0 = src block, 1 = dst block
        int cc = n & 255;
        int t = cc & 3;
        int ch = 2 * (cc >> 2) + (t & 1);
        const float* W = (t < 2) ? wf : ws;
        int col = blk ? k : (128 + k);
        Wpl[i] = f2bf(W[ch * ZDIM + col]);
    } else if (i < 512 * 128 + 256) {
        int j = i - 512 * 128;
        if (j < 128) wfe[l * 128 + j] = wf[j * ZDIM + 256] * LOG2E_F;
        else wse[l * 128 + (j - 128)] = ws[(j - 128) * ZDIM + 256] * LOG2E_F;
    }
}

// ---------------- MFMA node GEMM (merged cols, fragment-ordered B) ----------------
// P stores LOG2E-scaled pre-activations: f2bf((acc+bias)*LOG2E) — still exactly ONE
// bf16 rounding per value (R11's failure was double-rounding the weights; this is not that).
__launch_bounds__(512, 4)
__global__ void k_gemm(const unsigned short* __restrict__ xb,
                       const unsigned short* __restrict__ Wp,
                       const float* __restrict__ bf, const float* __restrict__ bs,
                       unsigned short* __restrict__ P) {
    __shared__ unsigned short smem[32 * EP_STRIDE];  // 32.5 KB; A tile uses first 16 KB
    unsigned short* A = smem;                        // A tile: 64 rows x 128 k
    const int row0 = blockIdx.x * 64;
    const int tid = threadIdx.x;

    {
        int r = tid >> 3, sub = tid & 7;
        const ushort8_t* src = (const ushort8_t*)(xb + (size_t)(row0 + r) * 128 + sub * 16);
        ushort8_t v0 = src[0], v1 = src[1];
        int h = r & 7;
        *(ushort8_t*)(A + r * 128 + (((sub * 2) ^ h) * 8)) = v0;
        *(ushort8_t*)(A + r * 128 + (((sub * 2 + 1) ^ h) * 8)) = v1;
    }
    __syncthreads();

    const int wid = tid >> 6, lane = tid & 63;
    const int l16 = lane & 15, lg = lane >> 4;

    float4v acc[4][4];
#pragma unroll
    for (int i = 0; i < 4; ++i)
#pragma unroll
        for (int j = 0; j < 4; ++j) acc[i][j] = (float4v){0.f, 0.f, 0.f, 0.f};

#pragma unroll
    for (int ks = 0; ks < 4; ++ks) {             // K = 128 in steps of 32
        short8 bfr[4];
#pragma unroll
        for (int cf = 0; cf < 4; ++cf) {
            int frag = (wid * 4 + cf) * 4 + ks;  // fragment-contiguous layout
            bfr[cf] = *(const short8*)(Wp + ((size_t)frag << 9) + lane * 8);
        }
#pragma unroll
        for (int rf = 0; rf < 4; ++rf) {
            int row = rf * 16 + l16;
            int kg = ks * 4 + lg;
            short8 af = *(const short8*)(A + row * 128 + ((kg ^ (row & 7)) * 8));
#pragma unroll
            for (int cf = 0; cf < 4; ++cf)
                acc[rf][cf] = __builtin_amdgcn_mfma_f32_16x16x32_bf16(
                    af, bfr[cf], acc[rf][cf], 0, 0, 0);
        }
    }

    float bias[4];
#pragma unroll
    for (int cf = 0; cf < 4; ++cf) {
        int n = wid * 64 + cf * 16 + l16;
        if (n < 256) bias[cf] = 0.f;
        else {
            int cc = n - 256;
            int t = cc & 3;
            int ch = 2 * (cc >> 2) + (t & 1);
            bias[cf] = (t < 2) ? bf[ch] : bs[ch];
        }
    }

#pragma unroll
    for (int p = 0; p < 2; ++p) {
        __syncthreads();
#pragma unroll
        for (int rfl = 0; rfl < 2; ++rfl) {
            int rf = 2 * p + rfl;
#pragma unroll
            for (int cf = 0; cf < 4; ++cf) {
                int col = wid * 64 + cf * 16 + l16;
#pragma unroll
                for (int r = 0; r < 4; ++r) {
                    int rowl = rfl * 16 + lg * 4 + r;     // 0..31
                    smem[rowl * EP_STRIDE + col] =
                        f2bf((acc[rf][cf][r] + bias[cf]) * LOG2E_F);
                }
            }
        }
        __syncthreads();
#pragma unroll
        for (int i = 0; i < 4; ++i) {
            int u = i * 512 + tid;
            int rw = u >> 6, ch = u & 63;
            *(ushort8_t*)(P + (size_t)(row0 + p * 32 + rw) * 512 + ch * 8) =
                *(const ushort8_t*)(smem + rw * EP_STRIDE + ch * 8);
        }
    }
}

// ---------------- CSR edge kernel: one wave per dst node, 2-deep pipelined 4-edge batches ----------------
// P is log2e-scaled: sigmoid = rcp(1+exp2(-g')); softplus accumulated in log2 units;
// single fma by LN2 per node at the end.
__launch_bounds__(64)
__global__ void k_edge_csr(const unsigned short* __restrict__ P,
                           const float* __restrict__ wfe, const float* __restrict__ wse,
                           const int* __restrict__ rowptr, const int2* __restrict__ csr,
                           float* __restrict__ x, unsigned short* __restrict__ xb) {
    int node = blockIdx.x;
    int lane = threadIdx.x;
    int beg = rowptr[node], end = rowptr[node + 1];
    ushort4 dv = *(const ushort4*)(P + (size_t)node * 512 + 256 + 4 * lane);
    float fi0 = bf2f(dv.x), fi1 = bf2f(dv.y);
    float si0 = bf2f(dv.z), si1 = bf2f(dv.w);
    float2 wf = ((const float2*)wfe)[lane];
    float2 wsv = ((const float2*)wse)[lane];
    float acc0 = 0.f, acc1 = 0.f;

    auto edge_math = [&](ushort4 sv, float eav) {
        float g0 = fi0 + bf2f(sv.x) + eav * wf.x;      // already *log2e
        float g1 = fi1 + bf2f(sv.y) + eav * wf.y;
        float c0 = si0 + bf2f(sv.z) + eav * wsv.x;
        float c1 = si1 + bf2f(sv.w) + eav * wsv.y;
        float sg0 = __builtin_amdgcn_rcpf(1.f + __builtin_amdgcn_exp2f(-g0));
        float sg1 = __builtin_amdgcn_rcpf(1.f + __builtin_amdgcn_exp2f(-g1));
        float l0 = __builtin_amdgcn_logf(1.f + __builtin_amdgcn_exp2f(-fabsf(c0)));
        float l1 = __builtin_amdgcn_logf(1.f + __builtin_amdgcn_exp2f(-fabsf(c1)));
        float sp0 = fmaxf(c0, 0.f) + l0;               // softplus in log2 units
        float sp1 = fmaxf(c1, 0.f) + l1;
        acc0 += sg0 * sp0;
        acc1 += sg1 * sp1;
    };

    auto load4 = [&](int eb, ushort4 (&sv)[4], float (&ea)[4]) {
#pragma unroll
        for (int i = 0; i < 4; ++i) {
            int2 c = csr[eb + i];
            int s = __builtin_amdgcn_readfirstlane(c.x);
            ea[i] = __uint_as_float(__builtin_amdgcn_readfirstlane((unsigned)c.y));
            sv[i] = *(const ushort4*)(P + (size_t)s * 512 + 4 * lane);
        }
    };

    int nb = (end - beg) >> 2;           // full 4-edge batches
    int e = beg + (nb << 2);
    if (nb > 0) {
        ushort4 sv0[4]; float ea0[4];
        load4(beg, sv0, ea0);
        for (int b = 1; b < nb; ++b) {
            ushort4 sv1[4]; float ea1[4];
            load4(beg + (b << 2), sv1, ea1);   // issue next batch's loads...
#pragma unroll
            for (int i = 0; i < 4; ++i) edge_math(sv0[i], ea0[i]);  // ...hidden under math
#pragma unroll
            for (int i = 0; i < 4; ++i) { sv0[i] = sv1[i]; ea0[i] = ea1[i]; }
        }
#pragma unroll
        for (int i = 0; i < 4; ++i) edge_math(sv0[i], ea0[i]);
    }
    for (; e < end; ++e) {
        int2 c0 = csr[e];
        int s0 = __builtin_amdgcn_readfirstlane(c0.x);
        float ea0 = __uint_as_float(__builtin_amdgcn_readfirstlane((unsigned)c0.y));
        ushort4 sv0 = *(const ushort4*)(P + (size_t)s0 * 512 + 4 * lane);
        edge_math(sv0, ea0);
    }

    float2* xd = (float2*)(x + (size_t)node * 128) + lane;
    float2 xv = *xd;
    xv.x = fmaf(acc0, LN2_F, xv.x);
    xv.y = fmaf(acc1, LN2_F, xv.y);
    *xd = xv;
    ushort2 xbv;
    xbv.x = f2bf(xv.x);
    xbv.y = f2bf(xv.y);
    ((ushort2*)(xb + (size_t)node * 128))[lane] = xbv;
}

// ---------------- fused mean-pool (4-way node-parallel) + FC head ----------------
__launch_bounds__(512)
__global__ void k_poolfc(const float* __restrict__ x, const int* __restrict__ gstart,
                         const float* __restrict__ fc_w, const float* __restrict__ fc_b,
                         const float* __restrict__ out_w, const float* __restrict__ out_b,
                         float* __restrict__ out) {
    int g = blockIdx.x;
    int tid = threadIdx.x;
    int h = tid & 127;
    int q = tid >> 7;                    // 0..3: node-quarter
    int s = gstart[g], e = gstart[g + 1];
    float sum = 0.f;
    for (int n = s + q; n < e; n += 4) sum += x[(size_t)n * HDIM + h];
    __shared__ float part[512];
    __shared__ float gin[128];
    __shared__ float gout[128];
    part[tid] = sum;
    __syncthreads();
    float cnt = fmaxf((float)(e - s), 1.0f);
    if (tid < 128) gin[h] = (part[h] + part[h + 128] + part[h + 256] + part[h + 384]) / cnt;
    __syncthreads();
    for (int l = 0; l < 3; ++l) {
        float acc = 0.f;
        if (tid < 128) {
            const float* W = fc_w + (size_t)l * HDIM * HDIM + (size_t)h * HDIM;
            acc = fc_b[l * HDIM + h];
#pragma unroll 4
            for (int k = 0; k < HDIM; k += 4) {
                float4 w4 = *(const float4*)(W + k);
                acc += gin[k] * w4.x + gin[k + 1] * w4.y + gin[k + 2] * w4.z + gin[k + 3] * w4.w;
            }
        }
        __syncthreads();
        if (tid < 128) gout[h] = acc;
        __syncthreads();
        if (tid < 128) gin[h] = gout[h];
        __syncthreads();
    }
    if (tid < 128) gout[h] = gin[h] * out_w[h];
    __syncthreads();
    if (tid < 64) gout[tid] += gout[tid + 64];
    __syncthreads();
    if (tid == 0) {
        float acc = 0.f;
        for (int i = 0; i < 64; ++i) acc += gout[i];
        out[g] = acc + out_b[0];
    }
}

extern "C" void kernel_launch(void* const* d_in, const int* in_sizes, int n_in,
                              void* d_out, int out_size, void* d_ws, size_t ws_size,
                              hipStream_t stream) {
    const int* atoms = (const int*)d_in[0];
    const float* pos = (const float*)d_in[1];
    const int* ei = (const int*)d_in[2];
    const int* batch = (const int*)d_in[3];
    const float* embed = (const float*)d_in[4];
    const float* lin_f_w = (const float*)d_in[5];
    const float* lin_f_b = (const float*)d_in[6];
    const float* lin_s_w = (const float*)d_in[7];
    const float* lin_s_b = (const float*)d_in[8];
    const float* fc_w = (const float*)d_in[9];
    const float* fc_b = (const float*)d_in[10];
    const float* out_w = (const float*)d_in[11];
    const float* out_b = (const float*)d_in[12];
    float* out = (float*)d_out;

    char* ws = (char*)d_ws;
    size_t off = 0;
    auto alloc = [&](size_t bytes) -> void* {
        void* p = ws + off;
        off += (bytes + 255) & ~(size_t)255;
        return p;
    };
    float* x            = (float*)alloc((size_t)N_NODES * HDIM * 4);
    unsigned short* xb  = (unsigned short*)alloc((size_t)N_NODES * HDIM * 2);
    unsigned short* P   = (unsigned short*)alloc((size_t)N_NODES * 512 * 2);
    unsigned short* Wp  = (unsigned short*)alloc((size_t)NLAYERS * 512 * 128 * 2);
    float* wfe          = (float*)alloc((size_t)NLAYERS * 128 * 4);
    float* wse          = (float*)alloc((size_t)NLAYERS * 128 * 4);
    int* deg            = (int*)alloc((size_t)N_NODES * 4);
    int* rowptr         = (int*)alloc((size_t)(N_NODES + 1) * 4);
    int* cursor         = (int*)alloc((size_t)N_NODES * 4);
    int* gstart         = (int*)alloc((size_t)(N_GRAPH + 1) * 4);
    int* bsum           = (int*)alloc((size_t)SCAN_BLOCKS * 4);
    int* boff           = (int*)alloc((size_t)SCAN_BLOCKS * 4);
    int2* csr           = (int2*)alloc((size_t)N_EDGES * 8);

    hipMemsetAsync(deg, 0, (size_t)N_NODES * 4, stream);

    k_embed_hist<<<(N_NODES * 32 + 255) / 256, 256, 0, stream>>>(atoms, embed, ei, x, xb, deg);
    k_scan1<<<SCAN_BLOCKS, 256, 0, stream>>>(deg, rowptr, bsum);
    k_scan2g<<<1, 256, 0, stream>>>(bsum, boff, rowptr, batch, gstart);
    k_scan3<<<SCAN_BLOCKS, 256, 0, stream>>>(boff, rowptr, cursor);
    k_scatter<<<(N_EDGES + 255) / 256, 256, 0, stream>>>(ei, pos, cursor, csr);
    k_pack<<<dim3(257, NLAYERS), 256, 0, stream>>>(lin_f_w, lin_s_w, Wp, wfe, wse);

    for (int l = 0; l < NLAYERS; ++l) {
        k_gemm<<<625, 512, 0, stream>>>(xb, Wp + (size_t)l * 512 * 128,
                                        lin_f_b + (size_t)l * HDIM,
                                        lin_s_b + (size_t)l * HDIM, P);
        k_edge_csr<<<N_NODES, 64, 0, stream>>>(P, wfe + (size_t)l * 128,
                                               wse + (size_t)l * 128, rowptr, csr,
                                               x, xb);
    }

    k_poolfc<<<N_GRAPH, 512, 0, stream>>>(x, gstart, fc_w, fc_b, out_w, out_b, out);
}

// Round 19
// 444.250 us; speedup vs baseline: 1.1926x; 1.0102x over previous
//
#include <hip/hip_runtime.h>
#include <cstdint>
#include <cstddef>

#define N_NODES 40000
#define N_EDGES 640000
#define N_GRAPH 256
#define HDIM 128
#define NLAYERS 5
#define ZDIM 257
#define SCAN_BLOCKS 157  // 157*256 = 40192 >= 40000
#define EP_STRIDE 520    // epilogue LDS row stride (ushorts): kills 4-way write conflict
#define EMBED_BLOCKS 5000   // (N_NODES*32)/256
#define PACK_BLOCKS 1285    // 257 * NLAYERS

typedef unsigned short ushort8_t __attribute__((ext_vector_type(8)));
typedef short short8 __attribute__((ext_vector_type(8)));
typedef float float4v __attribute__((ext_vector_type(4)));

static __device__ __forceinline__ float bf2f(unsigned short h) {
    return __uint_as_float((unsigned)h << 16);
}
static __device__ __forceinline__ unsigned short f2bf(float f) {
    unsigned u = __float_as_uint(f);
    unsigned r = u + 0x7fffu + ((u >> 16) & 1u);
    return (unsigned short)(r >> 16);
}

// ---------------- fused: embed gather + degree histogram + weight pack ----------------
// blocks [0, EMBED_BLOCKS): embed gather (+ edge-histogram on the same index range)
// blocks [EMBED_BLOCKS, EMBED_BLOCKS+PACK_BLOCKS): pack layer weights (independent work)
__global__ void k_embed_hist_pack(const int* __restrict__ atoms, const float* __restrict__ embed,
                                  const int* __restrict__ ei, float* __restrict__ x,
                                  unsigned short* __restrict__ xb, int* __restrict__ deg,
                                  const float* __restrict__ lin_f_w,
                                  const float* __restrict__ lin_s_w,
                                  unsigned short* __restrict__ Wp, float* __restrict__ wfe,
                                  float* __restrict__ wse) {
    if (blockIdx.x < EMBED_BLOCKS) {
        int i = blockIdx.x * 256 + threadIdx.x;
        if (i < N_NODES * 32) {
            int n = i >> 5, c = i & 31;
            int a = atoms[n];
            float4 v = ((const float4*)embed)[(size_t)a * 32 + c];
            ((float4*)x)[(size_t)n * 32 + c] = v;
            ushort4 w;
            w.x = f2bf(v.x); w.y = f2bf(v.y); w.z = f2bf(v.z); w.w = f2bf(v.w);
            ((ushort4*)xb)[(size_t)n * 32 + c] = w;
        }
        if (i < N_EDGES) {
            atomicAdd(&deg[ei[N_EDGES + i]], 1);
        }
    } else {
        // ---- pack: Wp[frag_id][lane][e], frag = (n>>4)*4+ks, lane = l16+16*lg ----
        int j = blockIdx.x - EMBED_BLOCKS;
        int l = j / 257;
        int i = (j % 257) * 256 + threadIdx.x;
        const float* wf = lin_f_w + (size_t)l * HDIM * ZDIM;
        const float* ws = lin_s_w + (size_t)l * HDIM * ZDIM;
        unsigned short* Wpl = Wp + (size_t)l * 512 * 128;
        if (i < 512 * 128) {
            int frag = i >> 9;               // 0..127
            int lane = (i >> 3) & 63;
            int e = i & 7;
            int fc = frag >> 2, ks = frag & 3;
            int l16 = lane & 15, lg = lane >> 4;
            int n = fc * 16 + l16;           // output column 0..511
            int k = ks * 32 + lg * 8 + e;    // k index 0..127
            int blk = n >> 8;                // 0 = src block, 1 = dst block
            int cc = n & 255;
            int t = cc & 3;
            int ch = 2 * (cc >> 2) + (t & 1);
            const float* W = (t < 2) ? wf : ws;
            int col = blk ? k : (128 + k);
            Wpl[i] = f2bf(W[ch * ZDIM + col]);
        } else if (i < 512 * 128 + 256) {
            int jj = i - 512 * 128;
            if (jj < 128) wfe[l * 128 + jj] = wf[jj * ZDIM + 256];
            else wse[l * 128 + (jj - 128)] = ws[(jj - 128) * ZDIM + 256];
        }
    }
}

// ---------------- 3-phase grid-wide exclusive scan ----------------
__global__ void k_scan1(const int* __restrict__ deg, int* __restrict__ rowptr,
                        int* __restrict__ bsum) {
    __shared__ int buf[256];
    int tid = threadIdx.x;
    int i = blockIdx.x * 256 + tid;
    int v = (i < N_NODES) ? deg[i] : 0;
    buf[tid] = v;
    __syncthreads();
    for (int off = 1; off < 256; off <<= 1) {
        int t = (tid >= off) ? buf[tid - off] : 0;
        __syncthreads();
        buf[tid] += t;
        __syncthreads();
    }
    if (i < N_NODES) rowptr[i] = buf[tid] - v;   // local exclusive
    if (tid == 255) bsum[blockIdx.x] = buf[255];
}

// phase 2 + graph boundaries (fused)
__global__ void k_scan2g(int* __restrict__ bsum, int* __restrict__ boff,
                         int* __restrict__ rowptr, const int* __restrict__ batch,
                         int* __restrict__ gstart) {
    __shared__ int buf[256];
    int tid = threadIdx.x;
    int v = (tid < SCAN_BLOCKS) ? bsum[tid] : 0;
    buf[tid] = v;
    __syncthreads();
    for (int off = 1; off < 256; off <<= 1) {
        int t = (tid >= off) ? buf[tid - off] : 0;
        __syncthreads();
        buf[tid] += t;
        __syncthreads();
    }
    if (tid < SCAN_BLOCKS) boff[tid] = buf[tid] - v;  // exclusive block offset
    if (tid == 255) rowptr[N_NODES] = buf[255];
    {
        int g = tid;
        int lo = 0, hi = N_NODES;
        while (lo < hi) {
            int mid = (lo + hi) >> 1;
            if (batch[mid] < g) lo = mid + 1; else hi = mid;
        }
        gstart[g] = lo;
        if (tid == 0) gstart[N_GRAPH] = N_NODES;
    }
}

__global__ void k_scan3(const int* __restrict__ boff, int* __restrict__ rowptr,
                        int* __restrict__ cursor) {
    int i = blockIdx.x * 256 + threadIdx.x;
    if (i >= N_NODES) return;
    int e = rowptr[i] + boff[blockIdx.x];
    rowptr[i] = e;
    cursor[i] = e;
}

// ---------------- scatter edges into CSR (by dst), computing ea inline ----------------
__global__ void k_scatter(const int* __restrict__ ei, const float* __restrict__ pos,
                          int* __restrict__ cursor, int2* __restrict__ csr) {
    int e = blockIdx.x * 256 + threadIdx.x;
    if (e >= N_EDGES) return;
    int s = ei[e], d = ei[N_EDGES + e];
    float dx = pos[3 * s] - pos[3 * d];
    float dy = pos[3 * s + 1] - pos[3 * d + 1];
    float dz = pos[3 * s + 2] - pos[3 * d + 2];
    float ea = sqrtf(dx * dx + dy * dy + dz * dz);
    int p = atomicAdd(&cursor[d], 1);
    csr[p] = make_int2(s, __float_as_int(ea));
}

// ---------------- MFMA node GEMM (merged cols, fragment-ordered B) ----------------
__launch_bounds__(512, 4)
__global__ void k_gemm(const unsigned short* __restrict__ xb,
                       const unsigned short* __restrict__ Wp,
                       const float* __restrict__ bf, const float* __restrict__ bs,
                       unsigned short* __restrict__ P) {
    __shared__ unsigned short smem[32 * EP_STRIDE];  // 32.5 KB; A tile uses first 16 KB
    unsigned short* A = smem;                        // A tile: 64 rows x 128 k
    const int row0 = blockIdx.x * 64;
    const int tid = threadIdx.x;

    {
        int r = tid >> 3, sub = tid & 7;
        const ushort8_t* src = (const ushort8_t*)(xb + (size_t)(row0 + r) * 128 + sub * 16);
        ushort8_t v0 = src[0], v1 = src[1];
        int h = r & 7;
        *(ushort8_t*)(A + r * 128 + (((sub * 2) ^ h) * 8)) = v0;
        *(ushort8_t*)(A + r * 128 + (((sub * 2 + 1) ^ h) * 8)) = v1;
    }
    __syncthreads();

    const int wid = tid >> 6, lane = tid & 63;
    const int l16 = lane & 15, lg = lane >> 4;

    float4v acc[4][4];
#pragma unroll
    for (int i = 0; i < 4; ++i)
#pragma unroll
        for (int j = 0; j < 4; ++j) acc[i][j] = (float4v){0.f, 0.f, 0.f, 0.f};

#pragma unroll
    for (int ks = 0; ks < 4; ++ks) {             // K = 128 in steps of 32
        short8 bfr[4];
#pragma unroll
        for (int cf = 0; cf < 4; ++cf) {
            int frag = (wid * 4 + cf) * 4 + ks;  // fragment-contiguous layout
            bfr[cf] = *(const short8*)(Wp + ((size_t)frag << 9) + lane * 8);
        }
#pragma unroll
        for (int rf = 0; rf < 4; ++rf) {
            int row = rf * 16 + l16;
            int kg = ks * 4 + lg;
            short8 af = *(const short8*)(A + row * 128 + ((kg ^ (row & 7)) * 8));
#pragma unroll
            for (int cf = 0; cf < 4; ++cf)
                acc[rf][cf] = __builtin_amdgcn_mfma_f32_16x16x32_bf16(
                    af, bfr[cf], acc[rf][cf], 0, 0, 0);
        }
    }

    float bias[4];
#pragma unroll
    for (int cf = 0; cf < 4; ++cf) {
        int n = wid * 64 + cf * 16 + l16;
        if (n < 256) bias[cf] = 0.f;
        else {
            int cc = n - 256;
            int t = cc & 3;
            int ch = 2 * (cc >> 2) + (t & 1);
            bias[cf] = (t < 2) ? bf[ch] : bs[ch];
        }
    }

#pragma unroll
    for (int p = 0; p < 2; ++p) {
        __syncthreads();
#pragma unroll
        for (int rfl = 0; rfl < 2; ++rfl) {
            int rf = 2 * p + rfl;
#pragma unroll
            for (int cf = 0; cf < 4; ++cf) {
                int col = wid * 64 + cf * 16 + l16;
#pragma unroll
                for (int r = 0; r < 4; ++r) {
                    int rowl = rfl * 16 + lg * 4 + r;     // 0..31
                    smem[rowl * EP_STRIDE + col] = f2bf(acc[rf][cf][r] + bias[cf]);
                }
            }
        }
        __syncthreads();
#pragma unroll
        for (int i = 0; i < 4; ++i) {
            int u = i * 512 + tid;
            int rw = u >> 6, ch = u & 63;
            *(ushort8_t*)(P + (size_t)(row0 + p * 32 + rw) * 512 + ch * 8) =
                *(const ushort8_t*)(smem + rw * EP_STRIDE + ch * 8);
        }
    }
}

// ---------------- CSR edge kernel: one wave per dst node, 2-deep pipelined 4-edge batches ----------------
__launch_bounds__(64)
__global__ void k_edge_csr(const unsigned short* __restrict__ P,
                           const float* __restrict__ wfe, const float* __restrict__ wse,
                           const int* __restrict__ rowptr, const int2* __restrict__ csr,
                           float* __restrict__ x, unsigned short* __restrict__ xb) {
    int node = blockIdx.x;
    int lane = threadIdx.x;
    int beg = rowptr[node], end = rowptr[node + 1];
    ushort4 dv = *(const ushort4*)(P + (size_t)node * 512 + 256 + 4 * lane);
    float fi0 = bf2f(dv.x), fi1 = bf2f(dv.y);
    float si0 = bf2f(dv.z), si1 = bf2f(dv.w);
    float2 wf = ((const float2*)wfe)[lane];
    float2 wsv = ((const float2*)wse)[lane];
    float acc0 = 0.f, acc1 = 0.f;
    const float LOG2E = 1.44269504f, LN2 = 0.69314718f;

    auto edge_math = [&](ushort4 sv, float eav) {
        float g0 = fi0 + bf2f(sv.x) + eav * wf.x;
        float g1 = fi1 + bf2f(sv.y) + eav * wf.y;
        float c0 = si0 + bf2f(sv.z) + eav * wsv.x;
        float c1 = si1 + bf2f(sv.w) + eav * wsv.y;
        float sg0 = __builtin_amdgcn_rcpf(1.f + __builtin_amdgcn_exp2f(-g0 * LOG2E));
        float sg1 = __builtin_amdgcn_rcpf(1.f + __builtin_amdgcn_exp2f(-g1 * LOG2E));
        float a0 = fabsf(c0), a1 = fabsf(c1);
        float l0 = __builtin_amdgcn_logf(1.f + __builtin_amdgcn_exp2f(-a0 * LOG2E)) * LN2;
        float l1 = __builtin_amdgcn_logf(1.f + __builtin_amdgcn_exp2f(-a1 * LOG2E)) * LN2;
        float sp0 = fmaxf(c0, 0.f) + l0;
        float sp1 = fmaxf(c1, 0.f) + l1;
        acc0 += sg0 * sp0;
        acc1 += sg1 * sp1;
    };

    auto load4 = [&](int eb, ushort4 (&sv)[4], float (&ea)[4]) {
#pragma unroll
        for (int i = 0; i < 4; ++i) {
            int2 c = csr[eb + i];
            int s = __builtin_amdgcn_readfirstlane(c.x);
            ea[i] = __uint_as_float(__builtin_amdgcn_readfirstlane((unsigned)c.y));
            sv[i] = *(const ushort4*)(P + (size_t)s * 512 + 4 * lane);
        }
    };

    int nb = (end - beg) >> 2;           // full 4-edge batches
    int e = beg + (nb << 2);
    if (nb > 0) {
        ushort4 sv0[4]; float ea0[4];
        load4(beg, sv0, ea0);
        for (int b = 1; b < nb; ++b) {
            ushort4 sv1[4]; float ea1[4];
            load4(beg + (b << 2), sv1, ea1);   // issue next batch's loads...
#pragma unroll
            for (int i = 0; i < 4; ++i) edge_math(sv0[i], ea0[i]);  // ...hidden under math
#pragma unroll
            for (int i = 0; i < 4; ++i) { sv0[i] = sv1[i]; ea0[i] = ea1[i]; }
        }
#pragma unroll
        for (int i = 0; i < 4; ++i) edge_math(sv0[i], ea0[i]);
    }
    for (; e < end; ++e) {
        int2 c0 = csr[e];
        int s0 = __builtin_amdgcn_readfirstlane(c0.x);
        float ea0 = __uint_as_float(__builtin_amdgcn_readfirstlane((unsigned)c0.y));
        ushort4 sv0 = *(const ushort4*)(P + (size_t)s0 * 512 + 4 * lane);
        edge_math(sv0, ea0);
    }

    float2* xd = (float2*)(x + (size_t)node * 128) + lane;
    float2 xv = *xd;
    xv.x += acc0;
    xv.y += acc1;
    *xd = xv;
    ushort2 xbv;
    xbv.x = f2bf(xv.x);
    xbv.y = f2bf(xv.y);
    ((ushort2*)(xb + (size_t)node * 128))[lane] = xbv;
}

// ---------------- fused mean-pool (4-way node-parallel) + FC head ----------------
__launch_bounds__(512)
__global__ void k_poolfc(const float* __restrict__ x, const int* __restrict__ gstart,
                         const float* __restrict__ fc_w, const float* __restrict__ fc_b,
                         const float* __restrict__ out_w, const float* __restrict__ out_b,
                         float* __restrict__ out) {
    int g = blockIdx.x;
    int tid = threadIdx.x;
    int h = tid & 127;
    int q = tid >> 7;                    // 0..3: node-quarter
    int s = gstart[g], e = gstart[g + 1];
    float sum = 0.f;
    for (int n = s + q; n < e; n += 4) sum += x[(size_t)n * HDIM + h];
    __shared__ float part[512];
    __shared__ float gin[128];
    __shared__ float gout[128];
    part[tid] = sum;
    __syncthreads();
    float cnt = fmaxf((float)(e - s), 1.0f);
    if (tid < 128) gin[h] = (part[h] + part[h + 128] + part[h + 256] + part[h + 384]) / cnt;
    __syncthreads();
    for (int l = 0; l < 3; ++l) {
        float acc = 0.f;
        if (tid < 128) {
            const float* W = fc_w + (size_t)l * HDIM * HDIM + (size_t)h * HDIM;
            acc = fc_b[l * HDIM + h];
#pragma unroll 4
            for (int k = 0; k < HDIM; k += 4) {
                float4 w4 = *(const float4*)(W + k);
                acc += gin[k] * w4.x + gin[k + 1] * w4.y + gin[k + 2] * w4.z + gin[k + 3] * w4.w;
            }
        }
        __syncthreads();
        if (tid < 128) gout[h] = acc;
        __syncthreads();
        if (tid < 128) gin[h] = gout[h];
        __syncthreads();
    }
    if (tid < 128) gout[h] = gin[h] * out_w[h];
    __syncthreads();
    if (tid < 64) gout[tid] += gout[tid + 64];
    __syncthreads();
    if (tid == 0) {
        float acc = 0.f;
        for (int i = 0; i < 64; ++i) acc += gout[i];
        out[g] = acc + out_b[0];
    }
}

extern "C" void kernel_launch(void* const* d_in, const int* in_sizes, int n_in,
                              void* d_out, int out_size, void* d_ws, size_t ws_size,
                              hipStream_t stream) {
    const int* atoms = (const int*)d_in[0];
    const float* pos = (const float*)d_in[1];
    const int* ei = (const int*)d_in[2];
    const int* batch = (const int*)d_in[3];
    const float* embed = (const float*)d_in[4];
    const float* lin_f_w = (const float*)d_in[5];
    const float* lin_f_b = (const float*)d_in[6];
    const float* lin_s_w = (const float*)d_in[7];
    const float* lin_s_b = (const float*)d_in[8];
    const float* fc_w = (const float*)d_in[9];
    const float* fc_b = (const float*)d_in[10];
    const float* out_w = (const float*)d_in[11];
    const float* out_b = (const float*)d_in[12];
    float* out = (float*)d_out;

    char* ws = (char*)d_ws;
    size_t off = 0;
    auto alloc = [&](size_t bytes) -> void* {
        void* p = ws + off;
        off += (bytes + 255) & ~(size_t)255;
        return p;
    };
    float* x            = (float*)alloc((size_t)N_NODES * HDIM * 4);
    unsigned short* xb  = (unsigned short*)alloc((size_t)N_NODES * HDIM * 2);
    unsigned short* P   = (unsigned short*)alloc((size_t)N_NODES * 512 * 2);
    unsigned short* Wp  = (unsigned short*)alloc((size_t)NLAYERS * 512 * 128 * 2);
    float* wfe          = (float*)alloc((size_t)NLAYERS * 128 * 4);
    float* wse          = (float*)alloc((size_t)NLAYERS * 128 * 4);
    int* deg            = (int*)alloc((size_t)N_NODES * 4);
    int* rowptr         = (int*)alloc((size_t)(N_NODES + 1) * 4);
    int* cursor         = (int*)alloc((size_t)N_NODES * 4);
    int* gstart         = (int*)alloc((size_t)(N_GRAPH + 1) * 4);
    int* bsum           = (int*)alloc((size_t)SCAN_BLOCKS * 4);
    int* boff           = (int*)alloc((size_t)SCAN_BLOCKS * 4);
    int2* csr           = (int2*)alloc((size_t)N_EDGES * 8);

    hipMemsetAsync(deg, 0, (size_t)N_NODES * 4, stream);

    k_embed_hist_pack<<<EMBED_BLOCKS + PACK_BLOCKS, 256, 0, stream>>>(
        atoms, embed, ei, x, xb, deg, lin_f_w, lin_s_w, Wp, wfe, wse);
    k_scan1<<<SCAN_BLOCKS, 256, 0, stream>>>(deg, rowptr, bsum);
    k_scan2g<<<1, 256, 0, stream>>>(bsum, boff, rowptr, batch, gstart);
    k_scan3<<<SCAN_BLOCKS, 256, 0, stream>>>(boff, rowptr, cursor);
    k_scatter<<<(N_EDGES + 255) / 256, 256, 0, stream>>>(ei, pos, cursor, csr);

    for (int l = 0; l < NLAYERS; ++l) {
        k_gemm<<<625, 512, 0, stream>>>(xb, Wp + (size_t)l * 512 * 128,
                                        lin_f_b + (size_t)l * HDIM,
                                        lin_s_b + (size_t)l * HDIM, P);
        k_edge_csr<<<N_NODES, 64, 0, stream>>>(P, wfe + (size_t)l * 128,
                                               wse + (size_t)l * 128, rowptr, csr,
                                               x, xb);
    }

    k_poolfc<<<N_GRAPH, 512, 0, stream>>>(x, gstart, fc_w, fc_b, out_w, out_b, out);
}